// Round 1
// baseline (21302.213 us; speedup 1.0000x reference)
//
#include <hip/hip_runtime.h>
#include <math.h>

#define H 768
#define NH 12
#define DH 64
#define SEQ 2048
#define BATCH 2
#define TOK (BATCH*SEQ)   // 4096 rows
#define LAYERS 6
#define VOCAB 50257

// ---------------------------------------------------------------- embed
__global__ __launch_bounds__(256) void embed_kernel(const int* __restrict__ ids,
                                                    const float* __restrict__ wte,
                                                    const float* __restrict__ wpe,
                                                    float* __restrict__ x) {
    int row = blockIdx.x;            // 0..TOK-1
    int s = row & (SEQ - 1);
    int id = ids[row];
    const float* wrow = wte + (size_t)id * H;
    const float* prow = wpe + (size_t)s * H;
    float* xrow = x + (size_t)row * H;
    for (int i = threadIdx.x; i < H; i += 256)
        xrow[i] = wrow[i] + prow[i];
}

// ---------------------------------------------------------------- layernorm
// in-row = blockIdx.x*rs + ro ; out-row = blockIdx.x (rs=1,ro=0 => identity map)
__global__ __launch_bounds__(256) void ln_kernel(const float* __restrict__ x,
                                                 const float* __restrict__ g,
                                                 const float* __restrict__ bb,
                                                 float* __restrict__ out,
                                                 int rs, int ro) {
    __shared__ float red[4];
    __shared__ float mean_s, rstd_s;
    int row = blockIdx.x * rs + ro;
    const float* xr = x + (size_t)row * H;
    int t = threadIdx.x;
    float v0 = xr[t], v1 = xr[t + 256], v2 = xr[t + 512];
    float s = v0 + v1 + v2;
    #pragma unroll
    for (int off = 32; off > 0; off >>= 1) s += __shfl_down(s, off);
    int lane = t & 63, wid = t >> 6;
    if (lane == 0) red[wid] = s;
    __syncthreads();
    if (t == 0) mean_s = (red[0] + red[1] + red[2] + red[3]) * (1.0f / 768.0f);
    __syncthreads();
    float m = mean_s;
    float d0 = v0 - m, d1 = v1 - m, d2 = v2 - m;
    float q = d0 * d0 + d1 * d1 + d2 * d2;
    #pragma unroll
    for (int off = 32; off > 0; off >>= 1) q += __shfl_down(q, off);
    if (lane == 0) red[wid] = q;
    __syncthreads();
    if (t == 0) rstd_s = rsqrtf((red[0] + red[1] + red[2] + red[3]) * (1.0f / 768.0f) + 1e-12f);
    __syncthreads();
    float r = rstd_s;
    float* orow = out + (size_t)blockIdx.x * H;
    orow[t]       = d0 * r * g[t]       + bb[t];
    orow[t + 256] = d1 * r * g[t + 256] + bb[t + 256];
    orow[t + 512] = d2 * r * g[t + 512] + bb[t + 512];
}

// ---------------------------------------------------------------- GEMM fp32
// C[M,N] = A[M,K] @ W[K,N]  (+bias) (+gelu) (+residual)
// mode 0: +bias ; mode 1: +bias +residual ; mode 2: gelu(no bias)
#define BM 64
#define BN 64
#define BK 16
__global__ __launch_bounds__(256) void gemm_kernel(const float* __restrict__ A,
                                                   const float* __restrict__ W,
                                                   const float* __restrict__ bias,
                                                   const float* __restrict__ res,
                                                   float* __restrict__ C,
                                                   int M, int N, int K, int mode) {
    __shared__ float As[BK][BM + 4];
    __shared__ float Ws[BK][BN];
    int bn = blockIdx.x * BN, bm = blockIdx.y * BM;
    int t = threadIdx.x;
    int tm = (t >> 4) << 2;   // 0..60
    int tn = (t & 15) << 2;   // 0..60
    float acc[4][4] = {};
    const float* Ap = A + (size_t)bm * K;
    const float* Wp = W + bn;
    for (int k0 = 0; k0 < K; k0 += BK) {
        // A tile 64x16 -> As[k][m]
        {
            int r = t >> 2;            // 0..63
            int c = (t & 3) << 2;      // 0,4,8,12
            float4 v = *(const float4*)(Ap + (size_t)r * K + k0 + c);
            As[c + 0][r] = v.x; As[c + 1][r] = v.y; As[c + 2][r] = v.z; As[c + 3][r] = v.w;
        }
        // W tile 16x64 -> Ws[k][n]
        {
            int r = t >> 4;            // 0..15
            int c = (t & 15) << 2;     // 0..60
            float4 v = *(const float4*)(Wp + (size_t)(k0 + r) * N + c);
            *(float4*)&Ws[r][c] = v;
        }
        __syncthreads();
        #pragma unroll
        for (int k = 0; k < BK; ++k) {
            float4 av = *(const float4*)&As[k][tm];
            float4 bv = *(const float4*)&Ws[k][tn];
            float a_[4] = {av.x, av.y, av.z, av.w};
            float b_[4] = {bv.x, bv.y, bv.z, bv.w};
            #pragma unroll
            for (int i = 0; i < 4; ++i)
                #pragma unroll
                for (int j = 0; j < 4; ++j)
                    acc[i][j] += a_[i] * b_[j];
        }
        __syncthreads();
    }
    #pragma unroll
    for (int i = 0; i < 4; ++i) {
        int m = bm + tm + i;
        float* crow = C + (size_t)m * N + bn + tn;
        const float* rrow = (mode == 1) ? (res + (size_t)m * N + bn + tn) : nullptr;
        #pragma unroll
        for (int j = 0; j < 4; ++j) {
            float v = acc[i][j];
            if (mode == 0 || mode == 1) v += bias[bn + tn + j];
            if (mode == 2) v = 0.5f * v * (1.0f + erff(v * 0.70710678118654752f));
            if (mode == 1) v += rrow[j];
            crow[j] = v;
        }
    }
}

// ---------------------------------------------------------------- attention
// one block (256 thr) per (b, head, q). qkv rows: [q(768) k(768) v(768)]
#define KTILE 128
__global__ __launch_bounds__(256) void attn_kernel(const float* __restrict__ qkv,
                                                   float* __restrict__ out) {
    __shared__ float qs[DH];
    __shared__ float Ks[KTILE][DH + 1];
    __shared__ float scores[SEQ];
    __shared__ float red[4];
    __shared__ float m_s, l_s;
    __shared__ float pv[4][DH];

    int idx = blockIdx.x;
    int q = idx & (SEQ - 1);
    int tmp = idx >> 11;
    int h = tmp % NH;
    int b = tmp / NH;
    const size_t rstride = 3 * H;
    const float* base = qkv + (size_t)b * SEQ * rstride;
    int t = threadIdx.x;
    int lane = t & 63, wid = t >> 6;

    if (t < DH) qs[t] = base[(size_t)q * rstride + h * DH + t];
    int nk = q + 1;

    float lmax = -INFINITY;
    for (int k0 = 0; k0 < nk; k0 += KTILE) {
        int kt = min(KTILE, nk - k0);
        __syncthreads();   // also covers qs on first iteration
        for (int i = t; i < KTILE * DH; i += 256) {
            int r = i >> 6, d = i & 63;
            Ks[r][d] = base[(size_t)(k0 + r) * rstride + H + h * DH + d];
        }
        __syncthreads();
        for (int k = t; k < kt; k += 256) {
            const float* kr = Ks[k];
            float s = 0.f;
            #pragma unroll
            for (int d = 0; d < DH; ++d) s += qs[d] * kr[d];
            s *= 0.125f;
            scores[k0 + k] = s;
            lmax = fmaxf(lmax, s);
        }
    }
    #pragma unroll
    for (int off = 32; off > 0; off >>= 1) lmax = fmaxf(lmax, __shfl_down(lmax, off));
    if (lane == 0) red[wid] = lmax;
    __syncthreads();
    if (t == 0) m_s = fmaxf(fmaxf(red[0], red[1]), fmaxf(red[2], red[3]));
    __syncthreads();
    float m = m_s;
    float lsum = 0.f;
    for (int k = t; k < nk; k += 256) {
        float e = __expf(scores[k] - m);
        scores[k] = e;
        lsum += e;
    }
    #pragma unroll
    for (int off = 32; off > 0; off >>= 1) lsum += __shfl_down(lsum, off);
    if (lane == 0) red[wid] = lsum;
    __syncthreads();
    if (t == 0) l_s = red[0] + red[1] + red[2] + red[3];
    __syncthreads();
    float inv = 1.0f / l_s;

    float acc = 0.f;
    for (int k = wid; k < nk; k += 4)
        acc += scores[k] * base[(size_t)k * rstride + 2 * H + h * DH + lane];
    pv[wid][lane] = acc;
    __syncthreads();
    if (t < DH) {
        float o = (pv[0][t] + pv[1][t] + pv[2][t] + pv[3][t]) * inv;
        out[((size_t)b * SEQ + q) * H + h * DH + t] = o;
    }
}

// ---------------------------------------------------------------- logits
// 4 waves/block, one (b,v) per wave: out[b,v] = dot(xf[b], wte[v])
__global__ __launch_bounds__(256) void logits_kernel(const float* __restrict__ xf,
                                                     const float* __restrict__ wte,
                                                     float* __restrict__ out) {
    int pair = blockIdx.x * 4 + (threadIdx.x >> 6);
    if (pair >= BATCH * VOCAB) return;
    int b = pair / VOCAB;
    int v = pair - b * VOCAB;
    int lane = threadIdx.x & 63;
    const float* w = wte + (size_t)v * H;
    const float* x = xf + (size_t)b * H;
    float s = 0.f;
    #pragma unroll
    for (int i = lane; i < H; i += 64) s += x[i] * w[i];
    #pragma unroll
    for (int off = 32; off > 0; off >>= 1) s += __shfl_down(s, off);
    if (lane == 0) out[(size_t)b * VOCAB + v] = s;
}

// ---------------------------------------------------------------- launch
extern "C" void kernel_launch(void* const* d_in, const int* in_sizes, int n_in,
                              void* d_out, int out_size, void* d_ws, size_t ws_size,
                              hipStream_t stream) {
    const int*   ids     = (const int*)d_in[0];
    const float* wte     = (const float*)d_in[1];
    const float* wpe     = (const float*)d_in[2];
    const float* ln1_g   = (const float*)d_in[3];
    const float* ln1_b   = (const float*)d_in[4];
    const float* qkv_w   = (const float*)d_in[5];
    const float* qkv_b   = (const float*)d_in[6];
    const float* dense_w = (const float*)d_in[7];
    const float* dense_b = (const float*)d_in[8];
    const float* ln2_g   = (const float*)d_in[9];
    const float* ln2_b   = (const float*)d_in[10];
    const float* fc1_w   = (const float*)d_in[11];
    const float* fc2_w   = (const float*)d_in[12];
    const float* fc2_b   = (const float*)d_in[13];
    const float* lnf_g   = (const float*)d_in[14];
    const float* lnf_b   = (const float*)d_in[15];
    float* outp = (float*)d_out;

    float* ws   = (float*)d_ws;
    float* x    = ws;                               // TOK*H
    float* h    = x + (size_t)TOK * H;              // TOK*H   (reused as attn out)
    float* qkvb = h + (size_t)TOK * H;              // TOK*3H
    float* ab   = qkvb + (size_t)TOK * 3 * H;       // TOK*2H
    float* xf   = ab + (size_t)TOK * 2 * H;         // BATCH*H
    float* attnb = h;

    embed_kernel<<<TOK, 256, 0, stream>>>(ids, wte, wpe, x);

    for (int l = 0; l < LAYERS; ++l) {
        ln_kernel<<<TOK, 256, 0, stream>>>(x, ln1_g + l * H, ln1_b + l * H, h, 1, 0);
        gemm_kernel<<<dim3(3 * H / BN, TOK / BM), 256, 0, stream>>>(
            h, qkv_w + (size_t)l * H * 3 * H, qkv_b + l * 3 * H, nullptr, qkvb,
            TOK, 3 * H, H, 0);
        attn_kernel<<<BATCH * NH * SEQ, 256, 0, stream>>>(qkvb, attnb);
        gemm_kernel<<<dim3(H / BN, TOK / BM), 256, 0, stream>>>(
            attnb, dense_w + (size_t)l * H * H, dense_b + l * H, x, x,
            TOK, H, H, 1);
        ln_kernel<<<TOK, 256, 0, stream>>>(x, ln2_g + l * H, ln2_b + l * H, h, 1, 0);
        gemm_kernel<<<dim3(2 * H / BN, TOK / BM), 256, 0, stream>>>(
            h, fc1_w + (size_t)l * H * 2 * H, nullptr, nullptr, ab,
            TOK, 2 * H, H, 2);
        gemm_kernel<<<dim3(H / BN, TOK / BM), 256, 0, stream>>>(
            ab, fc2_w + (size_t)l * 2 * H * H, fc2_b + l * H, x, x,
            TOK, H, 2 * H, 1);
    }

    // final LN on last position of each batch only
    ln_kernel<<<BATCH, 256, 0, stream>>>(x, lnf_g, lnf_b, xf, SEQ, SEQ - 1);
    logits_kernel<<<(BATCH * VOCAB + 3) / 4, 256, 0, stream>>>(xf, wte, outp);
}

// Round 2
// 5244.457 us; speedup vs baseline: 4.0619x; 4.0619x over previous
//
#include <hip/hip_runtime.h>
#include <math.h>

#define H 768
#define NH 12
#define DH 64
#define SEQ 2048
#define BATCH 2
#define TOK (BATCH*SEQ)   // 4096 rows
#define LAYERS 6
#define VOCAB 50257

// ---------------------------------------------------------------- embed
__global__ __launch_bounds__(256) void embed_kernel(const int* __restrict__ ids,
                                                    const float* __restrict__ wte,
                                                    const float* __restrict__ wpe,
                                                    float* __restrict__ x) {
    int row = blockIdx.x;            // 0..TOK-1
    int s = row & (SEQ - 1);
    int id = ids[row];
    const float* wrow = wte + (size_t)id * H;
    const float* prow = wpe + (size_t)s * H;
    float* xrow = x + (size_t)row * H;
    for (int i = threadIdx.x; i < H; i += 256)
        xrow[i] = wrow[i] + prow[i];
}

// ---------------------------------------------------------------- layernorm
__global__ __launch_bounds__(256) void ln_kernel(const float* __restrict__ x,
                                                 const float* __restrict__ g,
                                                 const float* __restrict__ bb,
                                                 float* __restrict__ out,
                                                 int rs, int ro) {
    __shared__ float red[4];
    __shared__ float mean_s, rstd_s;
    int row = blockIdx.x * rs + ro;
    const float* xr = x + (size_t)row * H;
    int t = threadIdx.x;
    float v0 = xr[t], v1 = xr[t + 256], v2 = xr[t + 512];
    float s = v0 + v1 + v2;
    #pragma unroll
    for (int off = 32; off > 0; off >>= 1) s += __shfl_down(s, off);
    int lane = t & 63, wid = t >> 6;
    if (lane == 0) red[wid] = s;
    __syncthreads();
    if (t == 0) mean_s = (red[0] + red[1] + red[2] + red[3]) * (1.0f / 768.0f);
    __syncthreads();
    float m = mean_s;
    float d0 = v0 - m, d1 = v1 - m, d2 = v2 - m;
    float q = d0 * d0 + d1 * d1 + d2 * d2;
    #pragma unroll
    for (int off = 32; off > 0; off >>= 1) q += __shfl_down(q, off);
    if (lane == 0) red[wid] = q;
    __syncthreads();
    if (t == 0) rstd_s = rsqrtf((red[0] + red[1] + red[2] + red[3]) * (1.0f / 768.0f) + 1e-12f);
    __syncthreads();
    float r = rstd_s;
    float* orow = out + (size_t)blockIdx.x * H;
    orow[t]       = d0 * r * g[t]       + bb[t];
    orow[t + 256] = d1 * r * g[t + 256] + bb[t + 256];
    orow[t + 512] = d2 * r * g[t + 512] + bb[t + 512];
}

// ---------------------------------------------------------------- GEMM fp32
// mode 0: +bias ; mode 1: +bias +residual ; mode 2: gelu(no bias)
#define BM 64
#define BN 64
#define BK 16
__global__ __launch_bounds__(256) void gemm_kernel(const float* __restrict__ A,
                                                   const float* __restrict__ W,
                                                   const float* __restrict__ bias,
                                                   const float* __restrict__ res,
                                                   float* __restrict__ C,
                                                   int M, int N, int K, int mode) {
    __shared__ float As[BK][BM + 4];
    __shared__ float Ws[BK][BN];
    int bn = blockIdx.x * BN, bm = blockIdx.y * BM;
    int t = threadIdx.x;
    int tm = (t >> 4) << 2;
    int tn = (t & 15) << 2;
    float acc[4][4] = {};
    const float* Ap = A + (size_t)bm * K;
    const float* Wp = W + bn;
    for (int k0 = 0; k0 < K; k0 += BK) {
        {
            int r = t >> 2;
            int c = (t & 3) << 2;
            float4 v = *(const float4*)(Ap + (size_t)r * K + k0 + c);
            As[c + 0][r] = v.x; As[c + 1][r] = v.y; As[c + 2][r] = v.z; As[c + 3][r] = v.w;
        }
        {
            int r = t >> 4;
            int c = (t & 15) << 2;
            float4 v = *(const float4*)(Wp + (size_t)(k0 + r) * N + c);
            *(float4*)&Ws[r][c] = v;
        }
        __syncthreads();
        #pragma unroll
        for (int k = 0; k < BK; ++k) {
            float4 av = *(const float4*)&As[k][tm];
            float4 bv = *(const float4*)&Ws[k][tn];
            float a_[4] = {av.x, av.y, av.z, av.w};
            float b_[4] = {bv.x, bv.y, bv.z, bv.w};
            #pragma unroll
            for (int i = 0; i < 4; ++i)
                #pragma unroll
                for (int j = 0; j < 4; ++j)
                    acc[i][j] += a_[i] * b_[j];
        }
        __syncthreads();
    }
    #pragma unroll
    for (int i = 0; i < 4; ++i) {
        int m = bm + tm + i;
        float* crow = C + (size_t)m * N + bn + tn;
        const float* rrow = (mode == 1) ? (res + (size_t)m * N + bn + tn) : nullptr;
        #pragma unroll
        for (int j = 0; j < 4; ++j) {
            float v = acc[i][j];
            if (mode == 0 || mode == 1) v += bias[bn + tn + j];
            if (mode == 2) v = 0.5f * v * (1.0f + erff(v * 0.70710678118654752f));
            if (mode == 1) v += rrow[j];
            crow[j] = v;
        }
    }
}

// ---------------------------------------------------------------- attention
// flash-v2 style: one block per (b, h, 64-row q-tile); online softmax.
// qkv row layout per token: [q(768) k(768) v(768)], head slice h*64..h*64+63
#define TQ 64
#define TK 64
#define AP 68   // LDS pitch (floats): rows 16B-aligned, lane bank-stride 4 => conflict-free
#define NQT (SEQ/TQ)
__global__ __launch_bounds__(256) void attn_kernel(const float* __restrict__ qkv,
                                                   float* __restrict__ out) {
    __shared__ float Qs[TQ][AP];
    __shared__ float Ks[TK][AP];
    __shared__ float Ps[TQ][AP];
    __shared__ float Vs[TK][AP];
    __shared__ float mrow[TQ], lrow[TQ], arow[TQ];

    int idx = blockIdx.x;
    int bh = idx % (BATCH * NH);
    int qt = (NQT - 1) - idx / (BATCH * NH);   // heavy tiles dispatched first
    int b = bh / NH, hh = bh % NH;
    int qbase = qt * TQ;
    const size_t rstride = 3 * H;
    const float* base = qkv + (size_t)b * SEQ * rstride + hh * DH;
    int t = threadIdx.x;

    int sr = t >> 2;            // staging row 0..63
    int sc = (t & 3) << 4;      // staging col 0,16,32,48

    // stage Q tile (once)
    {
        const float* src = base + (size_t)(qbase + sr) * rstride + sc;
        *(float4*)&Qs[sr][sc + 0]  = *(const float4*)(src + 0);
        *(float4*)&Qs[sr][sc + 4]  = *(const float4*)(src + 4);
        *(float4*)&Qs[sr][sc + 8]  = *(const float4*)(src + 8);
        *(float4*)&Qs[sr][sc + 12] = *(const float4*)(src + 12);
    }
    if (t < TQ) { mrow[t] = -INFINITY; lrow[t] = 0.0f; }

    int qg = t >> 4;            // 0..15 -> q rows 4*qg+i
    int kg = t & 15;            // S phase: k rows kg+16*j
    int dg = t & 15;            // PV phase: d cols 4*dg+j
    float o[4][4] = {};

    int ntiles = qt + 1;
    for (int kt = 0; kt < ntiles; ++kt) {
        int k0 = kt * TK;
        __syncthreads();   // prev-iter consumers done (covers Qs/state on iter 0)
        // stage K,V tiles
        {
            const float* ksrc = base + (size_t)(k0 + sr) * rstride + H + sc;
            const float* vsrc = base + (size_t)(k0 + sr) * rstride + 2 * H + sc;
            *(float4*)&Ks[sr][sc + 0]  = *(const float4*)(ksrc + 0);
            *(float4*)&Ks[sr][sc + 4]  = *(const float4*)(ksrc + 4);
            *(float4*)&Ks[sr][sc + 8]  = *(const float4*)(ksrc + 8);
            *(float4*)&Ks[sr][sc + 12] = *(const float4*)(ksrc + 12);
            *(float4*)&Vs[sr][sc + 0]  = *(const float4*)(vsrc + 0);
            *(float4*)&Vs[sr][sc + 4]  = *(const float4*)(vsrc + 4);
            *(float4*)&Vs[sr][sc + 8]  = *(const float4*)(vsrc + 8);
            *(float4*)&Vs[sr][sc + 12] = *(const float4*)(vsrc + 12);
        }
        __syncthreads();

        // ---- S = Q K^T (4x4 microtile per thread)
        float s00=0,s01=0,s02=0,s03=0, s10=0,s11=0,s12=0,s13=0;
        float s20=0,s21=0,s22=0,s23=0, s30=0,s31=0,s32=0,s33=0;
        #pragma unroll
        for (int d = 0; d < DH; d += 4) {
            float4 q0 = *(const float4*)&Qs[4*qg + 0][d];
            float4 q1 = *(const float4*)&Qs[4*qg + 1][d];
            float4 q2 = *(const float4*)&Qs[4*qg + 2][d];
            float4 q3 = *(const float4*)&Qs[4*qg + 3][d];
            float4 k0v = *(const float4*)&Ks[kg +  0][d];
            float4 k1v = *(const float4*)&Ks[kg + 16][d];
            float4 k2v = *(const float4*)&Ks[kg + 32][d];
            float4 k3v = *(const float4*)&Ks[kg + 48][d];
            s00 += q0.x*k0v.x + q0.y*k0v.y + q0.z*k0v.z + q0.w*k0v.w;
            s01 += q0.x*k1v.x + q0.y*k1v.y + q0.z*k1v.z + q0.w*k1v.w;
            s02 += q0.x*k2v.x + q0.y*k2v.y + q0.z*k2v.z + q0.w*k2v.w;
            s03 += q0.x*k3v.x + q0.y*k3v.y + q0.z*k3v.z + q0.w*k3v.w;
            s10 += q1.x*k0v.x + q1.y*k0v.y + q1.z*k0v.z + q1.w*k0v.w;
            s11 += q1.x*k1v.x + q1.y*k1v.y + q1.z*k1v.z + q1.w*k1v.w;
            s12 += q1.x*k2v.x + q1.y*k2v.y + q1.z*k2v.z + q1.w*k2v.w;
            s13 += q1.x*k3v.x + q1.y*k3v.y + q1.z*k3v.z + q1.w*k3v.w;
            s20 += q2.x*k0v.x + q2.y*k0v.y + q2.z*k0v.z + q2.w*k0v.w;
            s21 += q2.x*k1v.x + q2.y*k1v.y + q2.z*k1v.z + q2.w*k1v.w;
            s22 += q2.x*k2v.x + q2.y*k2v.y + q2.z*k2v.z + q2.w*k2v.w;
            s23 += q2.x*k3v.x + q2.y*k3v.y + q2.z*k3v.z + q2.w*k3v.w;
            s30 += q3.x*k0v.x + q3.y*k0v.y + q3.z*k0v.z + q3.w*k0v.w;
            s31 += q3.x*k1v.x + q3.y*k1v.y + q3.z*k1v.z + q3.w*k1v.w;
            s32 += q3.x*k2v.x + q3.y*k2v.y + q3.z*k2v.z + q3.w*k2v.w;
            s33 += q3.x*k3v.x + q3.y*k3v.y + q3.z*k3v.z + q3.w*k3v.w;
        }
        // scale + causal mask (diagonal tile only) + write P
        {
            float sv[4][4] = {{s00,s01,s02,s03},{s10,s11,s12,s13},
                              {s20,s21,s22,s23},{s30,s31,s32,s33}};
            bool diag = (k0 == qbase);
            #pragma unroll
            for (int i = 0; i < 4; ++i) {
                int qglob = qbase + 4*qg + i;
                #pragma unroll
                for (int j = 0; j < 4; ++j) {
                    float v = sv[i][j] * 0.125f;
                    if (diag && (k0 + kg + 16*j) > qglob) v = -INFINITY;
                    Ps[4*qg + i][kg + 16*j] = v;
                }
            }
        }
        __syncthreads();

        // ---- online softmax over this k-tile (4 threads per row)
        {
            int r = t >> 2, sub = t & 3;
            int kb = sub * 16;
            float tmax = -INFINITY;
            #pragma unroll
            for (int k = 0; k < 16; ++k) tmax = fmaxf(tmax, Ps[r][kb + k]);
            tmax = fmaxf(tmax, __shfl_xor(tmax, 1));
            tmax = fmaxf(tmax, __shfl_xor(tmax, 2));
            float mold = mrow[r];
            float mnew = fmaxf(mold, tmax);
            float suml = 0.f;
            #pragma unroll
            for (int k = 0; k < 16; ++k) {
                float e = __expf(Ps[r][kb + k] - mnew);
                Ps[r][kb + k] = e;
                suml += e;
            }
            suml += __shfl_xor(suml, 1);
            suml += __shfl_xor(suml, 2);
            if (sub == 0) {
                float al = __expf(mold - mnew);
                mrow[r] = mnew;
                lrow[r] = lrow[r] * al + suml;
                arow[r] = al;
            }
        }
        __syncthreads();

        // ---- O = O*alpha + P V
        {
            float al0 = arow[4*qg + 0], al1 = arow[4*qg + 1];
            float al2 = arow[4*qg + 2], al3 = arow[4*qg + 3];
            #pragma unroll
            for (int j = 0; j < 4; ++j) { o[0][j] *= al0; o[1][j] *= al1; o[2][j] *= al2; o[3][j] *= al3; }
            #pragma unroll
            for (int k4 = 0; k4 < TK; k4 += 4) {
                float4 p0 = *(const float4*)&Ps[4*qg + 0][k4];
                float4 p1 = *(const float4*)&Ps[4*qg + 1][k4];
                float4 p2 = *(const float4*)&Ps[4*qg + 2][k4];
                float4 p3 = *(const float4*)&Ps[4*qg + 3][k4];
                float4 v0 = *(const float4*)&Vs[k4 + 0][4*dg];
                float4 v1 = *(const float4*)&Vs[k4 + 1][4*dg];
                float4 v2 = *(const float4*)&Vs[k4 + 2][4*dg];
                float4 v3 = *(const float4*)&Vs[k4 + 3][4*dg];
                float pa[4][4] = {{p0.x,p0.y,p0.z,p0.w},{p1.x,p1.y,p1.z,p1.w},
                                  {p2.x,p2.y,p2.z,p2.w},{p3.x,p3.y,p3.z,p3.w}};
                float va[4][4] = {{v0.x,v0.y,v0.z,v0.w},{v1.x,v1.y,v1.z,v1.w},
                                  {v2.x,v2.y,v2.z,v2.w},{v3.x,v3.y,v3.z,v3.w}};
                #pragma unroll
                for (int i = 0; i < 4; ++i)
                    #pragma unroll
                    for (int kk = 0; kk < 4; ++kk) {
                        float p = pa[i][kk];
                        #pragma unroll
                        for (int j = 0; j < 4; ++j) o[i][j] += p * va[kk][j];
                    }
            }
        }
    }

    // epilogue: divide by l, write out (lrow stable since softmax barrier)
    #pragma unroll
    for (int i = 0; i < 4; ++i) {
        float inv = 1.0f / lrow[4*qg + i];
        float4 ov;
        ov.x = o[i][0] * inv; ov.y = o[i][1] * inv;
        ov.z = o[i][2] * inv; ov.w = o[i][3] * inv;
        *(float4*)&out[((size_t)(b * SEQ) + qbase + 4*qg + i) * H + hh * DH + 4*dg] = ov;
    }
}

// ---------------------------------------------------------------- logits
__global__ __launch_bounds__(256) void logits_kernel(const float* __restrict__ xf,
                                                     const float* __restrict__ wte,
                                                     float* __restrict__ out) {
    int pair = blockIdx.x * 4 + (threadIdx.x >> 6);
    if (pair >= BATCH * VOCAB) return;
    int b = pair / VOCAB;
    int v = pair - b * VOCAB;
    int lane = threadIdx.x & 63;
    const float* w = wte + (size_t)v * H;
    const float* x = xf + (size_t)b * H;
    float s = 0.f;
    #pragma unroll
    for (int i = lane; i < H; i += 64) s += x[i] * w[i];
    #pragma unroll
    for (int off = 32; off > 0; off >>= 1) s += __shfl_down(s, off);
    if (lane == 0) out[(size_t)b * VOCAB + v] = s;
}

// ---------------------------------------------------------------- launch
extern "C" void kernel_launch(void* const* d_in, const int* in_sizes, int n_in,
                              void* d_out, int out_size, void* d_ws, size_t ws_size,
                              hipStream_t stream) {
    const int*   ids     = (const int*)d_in[0];
    const float* wte     = (const float*)d_in[1];
    const float* wpe     = (const float*)d_in[2];
    const float* ln1_g   = (const float*)d_in[3];
    const float* ln1_b   = (const float*)d_in[4];
    const float* qkv_w   = (const float*)d_in[5];
    const float* qkv_b   = (const float*)d_in[6];
    const float* dense_w = (const float*)d_in[7];
    const float* dense_b = (const float*)d_in[8];
    const float* ln2_g   = (const float*)d_in[9];
    const float* ln2_b   = (const float*)d_in[10];
    const float* fc1_w   = (const float*)d_in[11];
    const float* fc2_w   = (const float*)d_in[12];
    const float* fc2_b   = (const float*)d_in[13];
    const float* lnf_g   = (const float*)d_in[14];
    const float* lnf_b   = (const float*)d_in[15];
    float* outp = (float*)d_out;

    float* ws   = (float*)d_ws;
    float* x    = ws;                               // TOK*H
    float* h    = x + (size_t)TOK * H;              // TOK*H   (reused as attn out)
    float* qkvb = h + (size_t)TOK * H;              // TOK*3H
    float* ab   = qkvb + (size_t)TOK * 3 * H;       // TOK*2H
    float* xf   = ab + (size_t)TOK * 2 * H;         // BATCH*H
    float* attnb = h;

    embed_kernel<<<TOK, 256, 0, stream>>>(ids, wte, wpe, x);

    for (int l = 0; l < LAYERS; ++l) {
        ln_kernel<<<TOK, 256, 0, stream>>>(x, ln1_g + l * H, ln1_b + l * H, h, 1, 0);
        gemm_kernel<<<dim3(3 * H / BN, TOK / BM), 256, 0, stream>>>(
            h, qkv_w + (size_t)l * H * 3 * H, qkv_b + l * 3 * H, nullptr, qkvb,
            TOK, 3 * H, H, 0);
        attn_kernel<<<BATCH * NH * NQT, 256, 0, stream>>>(qkvb, attnb);
        gemm_kernel<<<dim3(H / BN, TOK / BM), 256, 0, stream>>>(
            attnb, dense_w + (size_t)l * H * H, dense_b + l * H, x, x,
            TOK, H, H, 1);
        ln_kernel<<<TOK, 256, 0, stream>>>(x, ln2_g + l * H, ln2_b + l * H, h, 1, 0);
        gemm_kernel<<<dim3(2 * H / BN, TOK / BM), 256, 0, stream>>>(
            h, fc1_w + (size_t)l * H * 2 * H, nullptr, nullptr, ab,
            TOK, 2 * H, H, 2);
        gemm_kernel<<<dim3(H / BN, TOK / BM), 256, 0, stream>>>(
            ab, fc2_w + (size_t)l * 2 * H * H, fc2_b + l * H, x, x,
            TOK, H, 2 * H, 1);
    }

    ln_kernel<<<BATCH, 256, 0, stream>>>(x, lnf_g, lnf_b, xf, SEQ, SEQ - 1);
    logits_kernel<<<(BATCH * VOCAB + 3) / 4, 256, 0, stream>>>(xf, wte, outp);
}

// Round 3
// 2824.015 us; speedup vs baseline: 7.5432x; 1.8571x over previous
//
#include <hip/hip_runtime.h>
#include <math.h>

#define H 768
#define NH 12
#define DH 64
#define SEQ 2048
#define BATCH 2
#define TOK (BATCH*SEQ)   // 4096 rows
#define LAYERS 6
#define VOCAB 50257

typedef __attribute__((ext_vector_type(8))) short short8;
typedef __attribute__((ext_vector_type(4))) float floatx4;
typedef __attribute__((ext_vector_type(8))) unsigned short ushort8v;

__device__ __forceinline__ float bf2f(unsigned short u) {
    union { unsigned int i; float f; } v; v.i = ((unsigned int)u) << 16; return v.f;
}
__device__ __forceinline__ unsigned short f2b(float f) {
    union { float f; unsigned int i; } v; v.f = f;
    unsigned int u = v.i;
    return (unsigned short)((u + 0x7FFFu + ((u >> 16) & 1u)) >> 16);  // RNE
}
__device__ __forceinline__ void gload_lds16(const void* g, void* lds) {
    __builtin_amdgcn_global_load_lds((const __attribute__((address_space(1))) unsigned int*)g,
                                     (__attribute__((address_space(3))) unsigned int*)lds,
                                     16, 0, 0);
}

// ---------------------------------------------------------------- embed
__global__ __launch_bounds__(256) void embed_kernel(const int* __restrict__ ids,
                                                    const float* __restrict__ wte,
                                                    const float* __restrict__ wpe,
                                                    float* __restrict__ x) {
    int row = blockIdx.x;
    int s = row & (SEQ - 1);
    int id = ids[row];
    const float* wrow = wte + (size_t)id * H;
    const float* prow = wpe + (size_t)s * H;
    float* xrow = x + (size_t)row * H;
    for (int i = threadIdx.x; i < H; i += 256)
        xrow[i] = wrow[i] + prow[i];
}

// ---------------------------------------------------------------- layernorm (templated output dtype)
template <bool BF>
__global__ __launch_bounds__(256) void ln_kernel(const float* __restrict__ x,
                                                 const float* __restrict__ g,
                                                 const float* __restrict__ bb,
                                                 void* __restrict__ outv,
                                                 int rs, int ro) {
    __shared__ float red[4];
    __shared__ float mean_s, rstd_s;
    int row = blockIdx.x * rs + ro;
    const float* xr = x + (size_t)row * H;
    int t = threadIdx.x;
    float v0 = xr[t], v1 = xr[t + 256], v2 = xr[t + 512];
    float s = v0 + v1 + v2;
    #pragma unroll
    for (int off = 32; off > 0; off >>= 1) s += __shfl_down(s, off);
    int lane = t & 63, wid = t >> 6;
    if (lane == 0) red[wid] = s;
    __syncthreads();
    if (t == 0) mean_s = (red[0] + red[1] + red[2] + red[3]) * (1.0f / 768.0f);
    __syncthreads();
    float m = mean_s;
    float d0 = v0 - m, d1 = v1 - m, d2 = v2 - m;
    float q = d0 * d0 + d1 * d1 + d2 * d2;
    #pragma unroll
    for (int off = 32; off > 0; off >>= 1) q += __shfl_down(q, off);
    if (lane == 0) red[wid] = q;
    __syncthreads();
    if (t == 0) rstd_s = rsqrtf((red[0] + red[1] + red[2] + red[3]) * (1.0f / 768.0f) + 1e-12f);
    __syncthreads();
    float r = rstd_s;
    float o0 = d0 * r * g[t]       + bb[t];
    float o1 = d1 * r * g[t + 256] + bb[t + 256];
    float o2 = d2 * r * g[t + 512] + bb[t + 512];
    if (BF) {
        unsigned short* orow = (unsigned short*)outv + (size_t)blockIdx.x * H;
        orow[t] = f2b(o0); orow[t + 256] = f2b(o1); orow[t + 512] = f2b(o2);
    } else {
        float* orow = (float*)outv + (size_t)blockIdx.x * H;
        orow[t] = o0; orow[t + 256] = o1; orow[t + 512] = o2;
    }
}

// ---------------------------------------------------------------- weight fp32[K,N] -> bf16[N,K] transpose-convert
__global__ __launch_bounds__(256) void wconv_kernel(const float* __restrict__ W,
                                                    unsigned short* __restrict__ Wt,
                                                    int K, int N) {
    __shared__ float tile[64][65];
    int n0 = blockIdx.x * 64, k0 = blockIdx.y * 64;
    int t = threadIdx.x;
    int r = t >> 4, c = (t & 15) << 2;
    #pragma unroll
    for (int i = 0; i < 4; ++i) {
        float4 v = *(const float4*)(W + (size_t)(k0 + r + 16 * i) * N + n0 + c);
        tile[r + 16 * i][c + 0] = v.x; tile[r + 16 * i][c + 1] = v.y;
        tile[r + 16 * i][c + 2] = v.z; tile[r + 16 * i][c + 3] = v.w;
    }
    __syncthreads();
    #pragma unroll
    for (int i = 0; i < 4; ++i) {
        int n = r + 16 * i;
        ushort4 o;
        o.x = f2b(tile[c + 0][n]); o.y = f2b(tile[c + 1][n]);
        o.z = f2b(tile[c + 2][n]); o.w = f2b(tile[c + 3][n]);
        *(ushort4*)(Wt + (size_t)(n0 + n) * K + k0 + c) = o;
    }
}

// ---------------------------------------------------------------- bf16 MFMA GEMM (m97 structure)
// C[M,N] = A[M,K] @ Bt[N,K]^T ; mode 0: +bias -> bf16 ; 1: +bias+res -> fp32 ; 2: gelu -> bf16
#define GBM 128
#define GBN 128
#define GBK 32
__global__ __launch_bounds__(256) void gemm_bf16(const unsigned short* __restrict__ A,
                                                 const unsigned short* __restrict__ Bt,
                                                 const float* __restrict__ bias,
                                                 const float* __restrict__ res,
                                                 void* __restrict__ Cv,
                                                 int M, int N, int K, int mode) {
    __shared__ short As[GBM * GBK];   // [m][k] row-major, 8KB
    __shared__ short Bs[GBN * GBK];   // [n][k] row-major, 8KB
    int t = threadIdx.x;
    int w = t >> 6, lane = t & 63;
    int wr = w >> 1, wc = w & 1;
    int l16 = lane & 15, quad = lane >> 4;
    int bm = blockIdx.y * GBM, bn = blockIdx.x * GBN;

    floatx4 acc[4][4] = {};
    int srow = lane >> 2;
    int scol = (lane & 3) * 8;   // elements (16B chunk)
    char* AsB = (char*)As + w * 2048;
    char* BsB = (char*)Bs + w * 2048;
    const unsigned short* Aw0 = A + (size_t)(bm + w * 32 + srow) * K + scol;
    const unsigned short* Aw1 = Aw0 + (size_t)16 * K;
    const unsigned short* Bw0 = Bt + (size_t)(bn + w * 32 + srow) * K + scol;
    const unsigned short* Bw1 = Bw0 + (size_t)16 * K;

    for (int k0 = 0; k0 < K; k0 += GBK) {
        __syncthreads();
        gload_lds16(Aw0 + k0, AsB);
        gload_lds16(Aw1 + k0, AsB + 1024);
        gload_lds16(Bw0 + k0, BsB);
        gload_lds16(Bw1 + k0, BsB + 1024);
        __syncthreads();   // compiler emits vmcnt(0) drain before barrier
        short8 af[4], bfr[4];
        #pragma unroll
        for (int i = 0; i < 4; ++i)
            af[i] = *(const short8*)&As[(wr * 64 + i * 16 + l16) * GBK + quad * 8];
        #pragma unroll
        for (int i = 0; i < 4; ++i)
            bfr[i] = *(const short8*)&Bs[(wc * 64 + i * 16 + l16) * GBK + quad * 8];
        #pragma unroll
        for (int mi = 0; mi < 4; ++mi)
            #pragma unroll
            for (int ni = 0; ni < 4; ++ni)
                acc[mi][ni] = __builtin_amdgcn_mfma_f32_16x16x32_bf16(af[mi], bfr[ni], acc[mi][ni], 0, 0, 0);
    }

    // epilogue: C/D layout col=lane&15, row=quad*4+reg
    int r0 = bm + wr * 64 + quad * 4;
    int c0 = bn + wc * 64 + l16;
    #pragma unroll
    for (int ni = 0; ni < 4; ++ni) {
        int gc = c0 + ni * 16;
        float bv = (mode != 2) ? bias[gc] : 0.0f;
        #pragma unroll
        for (int mi = 0; mi < 4; ++mi) {
            int gr = r0 + mi * 16;
            #pragma unroll
            for (int reg = 0; reg < 4; ++reg) {
                float v = acc[mi][ni][reg];
                size_t idx = (size_t)(gr + reg) * N + gc;
                if (mode == 2) {
                    v = 0.5f * v * (1.0f + erff(v * 0.70710678118654752f));
                    ((unsigned short*)Cv)[idx] = f2b(v);
                } else if (mode == 0) {
                    ((unsigned short*)Cv)[idx] = f2b(v + bv);
                } else {
                    ((float*)Cv)[idx] = v + bv + res[idx];
                }
            }
        }
    }
}

// ---------------------------------------------------------------- attention (fp32 compute, bf16 I/O)
#define TQ 64
#define TK 64
#define AP 68
#define NQT (SEQ/TQ)
__global__ __launch_bounds__(256) void attn_kernel(const unsigned short* __restrict__ qkv,
                                                   unsigned short* __restrict__ out) {
    __shared__ float Qs[TQ][AP];
    __shared__ float Ks[TK][AP];
    __shared__ float Ps[TQ][AP];
    __shared__ float Vs[TK][AP];
    __shared__ float mrow[TQ], lrow[TQ], arow[TQ];

    int idx = blockIdx.x;
    int bh = idx % (BATCH * NH);
    int qt = (NQT - 1) - idx / (BATCH * NH);   // heavy tiles first
    int b = bh / NH, hh = bh % NH;
    int qbase = qt * TQ;
    const size_t rstride = 3 * H;
    const unsigned short* base = qkv + (size_t)b * SEQ * rstride + hh * DH;
    int t = threadIdx.x;

    int sr = t >> 2;
    int sc = (t & 3) << 4;      // 16-element chunks

    {
        const unsigned short* src = base + (size_t)(qbase + sr) * rstride + sc;
        ushort8v q0 = *(const ushort8v*)(src);
        ushort8v q1 = *(const ushort8v*)(src + 8);
        #pragma unroll
        for (int j = 0; j < 8; ++j) { Qs[sr][sc + j] = bf2f(q0[j]); Qs[sr][sc + 8 + j] = bf2f(q1[j]); }
    }
    if (t < TQ) { mrow[t] = -INFINITY; lrow[t] = 0.0f; }

    int qg = t >> 4;
    int kg = t & 15;
    int dg = t & 15;
    float o[4][4] = {};

    int ntiles = qt + 1;
    for (int kt = 0; kt < ntiles; ++kt) {
        int k0 = kt * TK;
        __syncthreads();
        {
            const unsigned short* ksrc = base + (size_t)(k0 + sr) * rstride + H + sc;
            const unsigned short* vsrc = base + (size_t)(k0 + sr) * rstride + 2 * H + sc;
            ushort8v ka = *(const ushort8v*)(ksrc);
            ushort8v kb = *(const ushort8v*)(ksrc + 8);
            ushort8v va = *(const ushort8v*)(vsrc);
            ushort8v vb = *(const ushort8v*)(vsrc + 8);
            #pragma unroll
            for (int j = 0; j < 8; ++j) {
                Ks[sr][sc + j] = bf2f(ka[j]); Ks[sr][sc + 8 + j] = bf2f(kb[j]);
                Vs[sr][sc + j] = bf2f(va[j]); Vs[sr][sc + 8 + j] = bf2f(vb[j]);
            }
        }
        __syncthreads();

        float s00=0,s01=0,s02=0,s03=0, s10=0,s11=0,s12=0,s13=0;
        float s20=0,s21=0,s22=0,s23=0, s30=0,s31=0,s32=0,s33=0;
        #pragma unroll
        for (int d = 0; d < DH; d += 4) {
            float4 q0 = *(const float4*)&Qs[4*qg + 0][d];
            float4 q1 = *(const float4*)&Qs[4*qg + 1][d];
            float4 q2 = *(const float4*)&Qs[4*qg + 2][d];
            float4 q3 = *(const float4*)&Qs[4*qg + 3][d];
            float4 k0v = *(const float4*)&Ks[kg +  0][d];
            float4 k1v = *(const float4*)&Ks[kg + 16][d];
            float4 k2v = *(const float4*)&Ks[kg + 32][d];
            float4 k3v = *(const float4*)&Ks[kg + 48][d];
            s00 += q0.x*k0v.x + q0.y*k0v.y + q0.z*k0v.z + q0.w*k0v.w;
            s01 += q0.x*k1v.x + q0.y*k1v.y + q0.z*k1v.z + q0.w*k1v.w;
            s02 += q0.x*k2v.x + q0.y*k2v.y + q0.z*k2v.z + q0.w*k2v.w;
            s03 += q0.x*k3v.x + q0.y*k3v.y + q0.z*k3v.z + q0.w*k3v.w;
            s10 += q1.x*k0v.x + q1.y*k0v.y + q1.z*k0v.z + q1.w*k0v.w;
            s11 += q1.x*k1v.x + q1.y*k1v.y + q1.z*k1v.z + q1.w*k1v.w;
            s12 += q1.x*k2v.x + q1.y*k2v.y + q1.z*k2v.z + q1.w*k2v.w;
            s13 += q1.x*k3v.x + q1.y*k3v.y + q1.z*k3v.z + q1.w*k3v.w;
            s20 += q2.x*k0v.x + q2.y*k0v.y + q2.z*k0v.z + q2.w*k0v.w;
            s21 += q2.x*k1v.x + q2.y*k1v.y + q2.z*k1v.z + q2.w*k1v.w;
            s22 += q2.x*k2v.x + q2.y*k2v.y + q2.z*k2v.z + q2.w*k2v.w;
            s23 += q2.x*k3v.x + q2.y*k3v.y + q2.z*k3v.z + q2.w*k3v.w;
            s30 += q3.x*k0v.x + q3.y*k0v.y + q3.z*k0v.z + q3.w*k0v.w;
            s31 += q3.x*k1v.x + q3.y*k1v.y + q3.z*k1v.z + q3.w*k1v.w;
            s32 += q3.x*k2v.x + q3.y*k2v.y + q3.z*k2v.z + q3.w*k2v.w;
            s33 += q3.x*k3v.x + q3.y*k3v.y + q3.z*k3v.z + q3.w*k3v.w;
        }
        {
            float sv[4][4] = {{s00,s01,s02,s03},{s10,s11,s12,s13},
                              {s20,s21,s22,s23},{s30,s31,s32,s33}};
            bool diag = (k0 == qbase);
            #pragma unroll
            for (int i = 0; i < 4; ++i) {
                int qglob = qbase + 4*qg + i;
                #pragma unroll
                for (int j = 0; j < 4; ++j) {
                    float v = sv[i][j] * 0.125f;
                    if (diag && (k0 + kg + 16*j) > qglob) v = -INFINITY;
                    Ps[4*qg + i][kg + 16*j] = v;
                }
            }
        }
        __syncthreads();

        {
            int r = t >> 2, sub = t & 3;
            int kb = sub * 16;
            float tmax = -INFINITY;
            #pragma unroll
            for (int k = 0; k < 16; ++k) tmax = fmaxf(tmax, Ps[r][kb + k]);
            tmax = fmaxf(tmax, __shfl_xor(tmax, 1));
            tmax = fmaxf(tmax, __shfl_xor(tmax, 2));
            float mold = mrow[r];
            float mnew = fmaxf(mold, tmax);
            float suml = 0.f;
            #pragma unroll
            for (int k = 0; k < 16; ++k) {
                float e = __expf(Ps[r][kb + k] - mnew);
                Ps[r][kb + k] = e;
                suml += e;
            }
            suml += __shfl_xor(suml, 1);
            suml += __shfl_xor(suml, 2);
            if (sub == 0) {
                float al = __expf(mold - mnew);
                mrow[r] = mnew;
                lrow[r] = lrow[r] * al + suml;
                arow[r] = al;
            }
        }
        __syncthreads();

        {
            float al0 = arow[4*qg + 0], al1 = arow[4*qg + 1];
            float al2 = arow[4*qg + 2], al3 = arow[4*qg + 3];
            #pragma unroll
            for (int j = 0; j < 4; ++j) { o[0][j] *= al0; o[1][j] *= al1; o[2][j] *= al2; o[3][j] *= al3; }
            #pragma unroll
            for (int k4 = 0; k4 < TK; k4 += 4) {
                float4 p0 = *(const float4*)&Ps[4*qg + 0][k4];
                float4 p1 = *(const float4*)&Ps[4*qg + 1][k4];
                float4 p2 = *(const float4*)&Ps[4*qg + 2][k4];
                float4 p3 = *(const float4*)&Ps[4*qg + 3][k4];
                float4 v0 = *(const float4*)&Vs[k4 + 0][4*dg];
                float4 v1 = *(const float4*)&Vs[k4 + 1][4*dg];
                float4 v2 = *(const float4*)&Vs[k4 + 2][4*dg];
                float4 v3 = *(const float4*)&Vs[k4 + 3][4*dg];
                float pa[4][4] = {{p0.x,p0.y,p0.z,p0.w},{p1.x,p1.y,p1.z,p1.w},
                                  {p2.x,p2.y,p2.z,p2.w},{p3.x,p3.y,p3.z,p3.w}};
                float va[4][4] = {{v0.x,v0.y,v0.z,v0.w},{v1.x,v1.y,v1.z,v1.w},
                                  {v2.x,v2.y,v2.z,v2.w},{v3.x,v3.y,v3.z,v3.w}};
                #pragma unroll
                for (int i = 0; i < 4; ++i)
                    #pragma unroll
                    for (int kk = 0; kk < 4; ++kk) {
                        float p = pa[i][kk];
                        #pragma unroll
                        for (int j = 0; j < 4; ++j) o[i][j] += p * va[kk][j];
                    }
            }
        }
    }

    #pragma unroll
    for (int i = 0; i < 4; ++i) {
        float inv = 1.0f / lrow[4*qg + i];
        ushort4 ov;
        ov.x = f2b(o[i][0] * inv); ov.y = f2b(o[i][1] * inv);
        ov.z = f2b(o[i][2] * inv); ov.w = f2b(o[i][3] * inv);
        *(ushort4*)&out[((size_t)(b * SEQ) + qbase + 4*qg + i) * H + hh * DH + 4*dg] = ov;
    }
}

// ---------------------------------------------------------------- logits (fp32)
__global__ __launch_bounds__(256) void logits_kernel(const float* __restrict__ xf,
                                                     const float* __restrict__ wte,
                                                     float* __restrict__ out) {
    int pair = blockIdx.x * 4 + (threadIdx.x >> 6);
    if (pair >= BATCH * VOCAB) return;
    int b = pair / VOCAB;
    int v = pair - b * VOCAB;
    int lane = threadIdx.x & 63;
    const float* w = wte + (size_t)v * H;
    const float* x = xf + (size_t)b * H;
    float s = 0.f;
    #pragma unroll
    for (int i = lane; i < H; i += 64) s += x[i] * w[i];
    #pragma unroll
    for (int off = 32; off > 0; off >>= 1) s += __shfl_down(s, off);
    if (lane == 0) out[(size_t)b * VOCAB + v] = s;
}

// ---------------------------------------------------------------- launch
extern "C" void kernel_launch(void* const* d_in, const int* in_sizes, int n_in,
                              void* d_out, int out_size, void* d_ws, size_t ws_size,
                              hipStream_t stream) {
    const int*   ids     = (const int*)d_in[0];
    const float* wte     = (const float*)d_in[1];
    const float* wpe     = (const float*)d_in[2];
    const float* ln1_g   = (const float*)d_in[3];
    const float* ln1_b   = (const float*)d_in[4];
    const float* qkv_w   = (const float*)d_in[5];
    const float* qkv_b   = (const float*)d_in[6];
    const float* dense_w = (const float*)d_in[7];
    const float* dense_b = (const float*)d_in[8];
    const float* ln2_g   = (const float*)d_in[9];
    const float* ln2_b   = (const float*)d_in[10];
    const float* fc1_w   = (const float*)d_in[11];
    const float* fc2_w   = (const float*)d_in[12];
    const float* fc2_b   = (const float*)d_in[13];
    const float* lnf_g   = (const float*)d_in[14];
    const float* lnf_b   = (const float*)d_in[15];
    float* outp = (float*)d_out;

    char* p = (char*)d_ws;
    float* x             = (float*)p;          p += (size_t)TOK * H * 4;
    unsigned short* h    = (unsigned short*)p; p += (size_t)TOK * H * 2;
    unsigned short* qkvb = (unsigned short*)p; p += (size_t)TOK * 3 * H * 2;
    unsigned short* attnb= (unsigned short*)p; p += (size_t)TOK * H * 2;
    unsigned short* ab   = (unsigned short*)p; p += (size_t)TOK * 2 * H * 2;
    unsigned short* wt   = (unsigned short*)p; p += (size_t)2304 * 768 * 2;  // max weight
    float* xf            = (float*)p;          p += (size_t)BATCH * H * 4;

    embed_kernel<<<TOK, 256, 0, stream>>>(ids, wte, wpe, x);

    for (int l = 0; l < LAYERS; ++l) {
        ln_kernel<true><<<TOK, 256, 0, stream>>>(x, ln1_g + l * H, ln1_b + l * H, h, 1, 0);
        wconv_kernel<<<dim3(2304 / 64, 768 / 64), 256, 0, stream>>>(
            qkv_w + (size_t)l * H * 3 * H, wt, 768, 2304);
        gemm_bf16<<<dim3(2304 / GBN, TOK / GBM), 256, 0, stream>>>(
            h, wt, qkv_b + l * 3 * H, nullptr, qkvb, TOK, 2304, 768, 0);
        attn_kernel<<<BATCH * NH * NQT, 256, 0, stream>>>(qkvb, attnb);
        wconv_kernel<<<dim3(768 / 64, 768 / 64), 256, 0, stream>>>(
            dense_w + (size_t)l * H * H, wt, 768, 768);
        gemm_bf16<<<dim3(768 / GBN, TOK / GBM), 256, 0, stream>>>(
            attnb, wt, dense_b + l * H, x, x, TOK, 768, 768, 1);
        ln_kernel<true><<<TOK, 256, 0, stream>>>(x, ln2_g + l * H, ln2_b + l * H, h, 1, 0);
        wconv_kernel<<<dim3(1536 / 64, 768 / 64), 256, 0, stream>>>(
            fc1_w + (size_t)l * H * 2 * H, wt, 768, 1536);
        gemm_bf16<<<dim3(1536 / GBN, TOK / GBM), 256, 0, stream>>>(
            h, wt, nullptr, nullptr, ab, TOK, 1536, 768, 2);
        wconv_kernel<<<dim3(768 / 64, 1536 / 64), 256, 0, stream>>>(
            fc2_w + (size_t)l * 2 * H * H, wt, 1536, 768);
        gemm_bf16<<<dim3(768 / GBN, TOK / GBM), 256, 0, stream>>>(
            ab, wt, fc2_b + l * H, x, x, TOK, 768, 1536, 1);
    }

    ln_kernel<false><<<BATCH, 256, 0, stream>>>(x, lnf_g, lnf_b, xf, SEQ, SEQ - 1);
    logits_kernel<<<(BATCH * VOCAB + 3) / 4, 256, 0, stream>>>(xf, wte, outp);
}

// Round 4
// 1943.669 us; speedup vs baseline: 10.9598x; 1.4529x over previous
//
#include <hip/hip_runtime.h>
#include <math.h>

#define H 768
#define NH 12
#define DH 64
#define SEQ 2048
#define BATCH 2
#define TOK (BATCH*SEQ)   // 4096 rows
#define LAYERS 6
#define VOCAB 50257

typedef __attribute__((ext_vector_type(8))) short short8;
typedef __attribute__((ext_vector_type(4))) float floatx4;
typedef __attribute__((ext_vector_type(8))) unsigned short ushort8v;

__device__ __forceinline__ float bf2f(unsigned short u) {
    union { unsigned int i; float f; } v; v.i = ((unsigned int)u) << 16; return v.f;
}
__device__ __forceinline__ unsigned short f2b(float f) {
    union { float f; unsigned int i; } v; v.f = f;
    unsigned int u = v.i;
    return (unsigned short)((u + 0x7FFFu + ((u >> 16) & 1u)) >> 16);  // RNE
}
__device__ __forceinline__ void gload_lds16(const void* g, void* lds) {
    __builtin_amdgcn_global_load_lds((const __attribute__((address_space(1))) unsigned int*)g,
                                     (__attribute__((address_space(3))) unsigned int*)lds,
                                     16, 0, 0);
}

// ---------------------------------------------------------------- embed
__global__ __launch_bounds__(256) void embed_kernel(const int* __restrict__ ids,
                                                    const float* __restrict__ wte,
                                                    const float* __restrict__ wpe,
                                                    float* __restrict__ x) {
    int row = blockIdx.x;
    int s = row & (SEQ - 1);
    int id = ids[row];
    const float* wrow = wte + (size_t)id * H;
    const float* prow = wpe + (size_t)s * H;
    float* xrow = x + (size_t)row * H;
    for (int i = threadIdx.x; i < H; i += 256)
        xrow[i] = wrow[i] + prow[i];
}

// ---------------------------------------------------------------- layernorm
template <bool BF>
__global__ __launch_bounds__(256) void ln_kernel(const float* __restrict__ x,
                                                 const float* __restrict__ g,
                                                 const float* __restrict__ bb,
                                                 void* __restrict__ outv,
                                                 int rs, int ro) {
    __shared__ float red[4];
    __shared__ float mean_s, rstd_s;
    int row = blockIdx.x * rs + ro;
    const float* xr = x + (size_t)row * H;
    int t = threadIdx.x;
    float v0 = xr[t], v1 = xr[t + 256], v2 = xr[t + 512];
    float s = v0 + v1 + v2;
    #pragma unroll
    for (int off = 32; off > 0; off >>= 1) s += __shfl_down(s, off);
    int lane = t & 63, wid = t >> 6;
    if (lane == 0) red[wid] = s;
    __syncthreads();
    if (t == 0) mean_s = (red[0] + red[1] + red[2] + red[3]) * (1.0f / 768.0f);
    __syncthreads();
    float m = mean_s;
    float d0 = v0 - m, d1 = v1 - m, d2 = v2 - m;
    float q = d0 * d0 + d1 * d1 + d2 * d2;
    #pragma unroll
    for (int off = 32; off > 0; off >>= 1) q += __shfl_down(q, off);
    if (lane == 0) red[wid] = q;
    __syncthreads();
    if (t == 0) rstd_s = rsqrtf((red[0] + red[1] + red[2] + red[3]) * (1.0f / 768.0f) + 1e-12f);
    __syncthreads();
    float r = rstd_s;
    float o0 = d0 * r * g[t]       + bb[t];
    float o1 = d1 * r * g[t + 256] + bb[t + 256];
    float o2 = d2 * r * g[t + 512] + bb[t + 512];
    if (BF) {
        unsigned short* orow = (unsigned short*)outv + (size_t)blockIdx.x * H;
        orow[t] = f2b(o0); orow[t + 256] = f2b(o1); orow[t + 512] = f2b(o2);
    } else {
        float* orow = (float*)outv + (size_t)blockIdx.x * H;
        orow[t] = o0; orow[t + 256] = o1; orow[t + 512] = o2;
    }
}

// ---------------------------------------------------------------- weight fp32[K,N] -> bf16[N,K]
__global__ __launch_bounds__(256) void wconv_kernel(const float* __restrict__ W,
                                                    unsigned short* __restrict__ Wt,
                                                    int K, int N) {
    __shared__ float tile[64][65];
    int n0 = blockIdx.x * 64, k0 = blockIdx.y * 64;
    int t = threadIdx.x;
    int r = t >> 4, c = (t & 15) << 2;
    #pragma unroll
    for (int i = 0; i < 4; ++i) {
        float4 v = *(const float4*)(W + (size_t)(k0 + r + 16 * i) * N + n0 + c);
        tile[r + 16 * i][c + 0] = v.x; tile[r + 16 * i][c + 1] = v.y;
        tile[r + 16 * i][c + 2] = v.z; tile[r + 16 * i][c + 3] = v.w;
    }
    __syncthreads();
    #pragma unroll
    for (int i = 0; i < 4; ++i) {
        int n = r + 16 * i;
        ushort4 o;
        o.x = f2b(tile[c + 0][n]); o.y = f2b(tile[c + 1][n]);
        o.z = f2b(tile[c + 2][n]); o.w = f2b(tile[c + 3][n]);
        *(ushort4*)(Wt + (size_t)(n0 + n) * K + k0 + c) = o;
    }
}

// ---------------------------------------------------------------- bf16 MFMA GEMM (m97 structure)
// C[M,N] = A[M,K] @ Bt[N,K]^T
// mode 0: qkv epilogue (+bias; Q cols pre-scaled 1/8; V cols -> vtb transposed) -> bf16
// mode 1: +bias+res -> fp32 ; mode 2: gelu -> bf16
#define GBM 128
#define GBN 128
#define GBK 32
__global__ __launch_bounds__(256) void gemm_bf16(const unsigned short* __restrict__ A,
                                                 const unsigned short* __restrict__ Bt,
                                                 const float* __restrict__ bias,
                                                 const float* __restrict__ res,
                                                 void* __restrict__ Cv,
                                                 unsigned short* __restrict__ vtb,
                                                 int M, int N, int K, int mode) {
    __shared__ short As[GBM * GBK];   // [m][k] row-major
    __shared__ short Bs[GBN * GBK];   // [n][k] row-major
    int t = threadIdx.x;
    int w = t >> 6, lane = t & 63;
    int wr = w >> 1, wc = w & 1;
    int l16 = lane & 15, quad = lane >> 4;
    int bm = blockIdx.y * GBM, bn = blockIdx.x * GBN;

    floatx4 acc[4][4] = {};
    int srow = lane >> 2;
    int scol = (lane & 3) * 8;
    char* AsB = (char*)As + w * 2048;
    char* BsB = (char*)Bs + w * 2048;
    const unsigned short* Aw0 = A + (size_t)(bm + w * 32 + srow) * K + scol;
    const unsigned short* Aw1 = Aw0 + (size_t)16 * K;
    const unsigned short* Bw0 = Bt + (size_t)(bn + w * 32 + srow) * K + scol;
    const unsigned short* Bw1 = Bw0 + (size_t)16 * K;

    for (int k0 = 0; k0 < K; k0 += GBK) {
        __syncthreads();
        gload_lds16(Aw0 + k0, AsB);
        gload_lds16(Aw1 + k0, AsB + 1024);
        gload_lds16(Bw0 + k0, BsB);
        gload_lds16(Bw1 + k0, BsB + 1024);
        __syncthreads();
        short8 af[4], bfr[4];
        #pragma unroll
        for (int i = 0; i < 4; ++i)
            af[i] = *(const short8*)&As[(wr * 64 + i * 16 + l16) * GBK + quad * 8];
        #pragma unroll
        for (int i = 0; i < 4; ++i)
            bfr[i] = *(const short8*)&Bs[(wc * 64 + i * 16 + l16) * GBK + quad * 8];
        #pragma unroll
        for (int mi = 0; mi < 4; ++mi)
            #pragma unroll
            for (int ni = 0; ni < 4; ++ni)
                acc[mi][ni] = __builtin_amdgcn_mfma_f32_16x16x32_bf16(af[mi], bfr[ni], acc[mi][ni], 0, 0, 0);
    }

    int r0 = bm + wr * 64 + quad * 4;
    int c0 = bn + wc * 64 + l16;
    #pragma unroll
    for (int ni = 0; ni < 4; ++ni) {
        int gc = c0 + ni * 16;
        float bv = (mode != 2) ? bias[gc] : 0.0f;
        #pragma unroll
        for (int mi = 0; mi < 4; ++mi) {
            int gr = r0 + mi * 16;
            if (mode == 0 && gc >= 1536) {
                // V column -> vtb[b][h][d][s] transposed, 4 consecutive s packed
                int hd = gc - 1536;
                int bb_ = gr >> 11, ss = gr & 2047;
                ushort4 o4;
                o4.x = f2b(acc[mi][ni][0] + bv);
                o4.y = f2b(acc[mi][ni][1] + bv);
                o4.z = f2b(acc[mi][ni][2] + bv);
                o4.w = f2b(acc[mi][ni][3] + bv);
                *(ushort4*)&vtb[((size_t)(bb_ * NH + (hd >> 6)) * 64 + (hd & 63)) * SEQ + ss] = o4;
            } else {
                #pragma unroll
                for (int reg = 0; reg < 4; ++reg) {
                    float v = acc[mi][ni][reg];
                    size_t idx = (size_t)(gr + reg) * N + gc;
                    if (mode == 2) {
                        v = 0.5f * v * (1.0f + erff(v * 0.70710678118654752f));
                        ((unsigned short*)Cv)[idx] = f2b(v);
                    } else if (mode == 0) {
                        v += bv;
                        if (gc < 768) v *= 0.125f;   // pre-scale Q (exact in bf16)
                        ((unsigned short*)Cv)[idx] = f2b(v);
                    } else {
                        ((float*)Cv)[idx] = v + bv + res[idx];
                    }
                }
            }
        }
    }
}

// ---------------------------------------------------------------- attention: MFMA flash
// one block per (b, h, 128-row q-tile); 4 waves x 32 q-rows; K-tiles of 64.
// S^T = K·Q^T (C-layout: row=k, col=q) -> reg softmax -> Pt LDS (wave-private,
// A-layout) -> O = P·V^T via Vts[d][k].
#define ATQ 128
#define ATK 64
#define PTP 72          // Pt pitch: 144B rows (16B-aligned, bank-balanced)
#define NQTA (SEQ/ATQ)  // 16
__global__ __launch_bounds__(256) void attn_mfma(const unsigned short* __restrict__ qkv,
                                                 const unsigned short* __restrict__ vt,
                                                 unsigned short* __restrict__ out) {
    __shared__ unsigned short Qs[ATQ * 64];       // [q][d]   16KB
    __shared__ unsigned short Ks[ATK * 64];       // [k][d]    8KB
    __shared__ unsigned short Vts[64 * ATK];      // [d][k]    8KB
    __shared__ unsigned short Pt[4][32 * PTP];    // per-wave [q][k] 18KB

    int idx = blockIdx.x;
    int bh = idx % (BATCH * NH);
    int qt_blk = (NQTA - 1) - idx / (BATCH * NH);   // heavy tiles first
    int b = bh / NH, hh = bh % NH;
    int qbase = qt_blk * ATQ;
    const size_t rstride = 3 * H;
    const unsigned short* base = qkv + (size_t)b * SEQ * rstride;
    const unsigned short* vbase = vt + (size_t)bh * DH * SEQ;

    int t = threadIdx.x;
    int w = t >> 6, lane = t & 63;
    int l16 = lane & 15, quad = lane >> 4;

    // stage Q tile (wave w: rows w*32 .. w*32+31)
    #pragma unroll
    for (int i = 0; i < 4; ++i) {
        int row = w * 32 + i * 8 + (lane >> 3);
        int col = (lane & 7) * 8;
        gload_lds16(base + (size_t)(qbase + row) * rstride + hh * 64 + col,
                    Qs + w * 2048 + i * 512);
    }
    __syncthreads();

    short8 qf[2][2];
    #pragma unroll
    for (int qt = 0; qt < 2; ++qt)
        #pragma unroll
        for (int ch = 0; ch < 2; ++ch)
            qf[qt][ch] = *(const short8*)&Qs[(w * 32 + qt * 16 + l16) * 64 + ch * 32 + quad * 8];

    float mst[2] = {-INFINITY, -INFINITY};
    float lst[2] = {0.0f, 0.0f};
    floatx4 oacc[2][4] = {};

    int ntiles = (qbase + ATQ) / ATK;
    for (int kt = 0; kt < ntiles; ++kt) {
        int k0 = kt * ATK;
        __syncthreads();   // prev-iter consumers of Ks/Vts done
        #pragma unroll
        for (int i = 0; i < 2; ++i) {
            int row = w * 16 + i * 8 + (lane >> 3);
            int col = (lane & 7) * 8;
            gload_lds16(base + (size_t)(k0 + row) * rstride + H + hh * 64 + col,
                        Ks + w * 1024 + i * 512);
            gload_lds16(vbase + (size_t)row * SEQ + k0 + col,
                        Vts + w * 1024 + i * 512);
        }
        __syncthreads();

        // S^T = K·Q^T  (scores pre-scaled via Q)
        floatx4 sacc[4][2] = {};
        #pragma unroll
        for (int ch = 0; ch < 2; ++ch) {
            short8 kf[4];
            #pragma unroll
            for (int i = 0; i < 4; ++i)
                kf[i] = *(const short8*)&Ks[(i * 16 + l16) * 64 + ch * 32 + quad * 8];
            #pragma unroll
            for (int i = 0; i < 4; ++i)
                #pragma unroll
                for (int qt = 0; qt < 2; ++qt)
                    sacc[i][qt] = __builtin_amdgcn_mfma_f32_16x16x32_bf16(kf[i], qf[qt][ch], sacc[i][qt], 0, 0, 0);
        }

        bool needmask = (k0 + ATK - 1) > (qbase + w * 32);
        #pragma unroll
        for (int qt = 0; qt < 2; ++qt) {
            int qg = qbase + w * 32 + qt * 16 + l16;
            float tm = -INFINITY;
            #pragma unroll
            for (int i = 0; i < 4; ++i)
                #pragma unroll
                for (int r = 0; r < 4; ++r) {
                    float v = sacc[i][qt][r];
                    int kg = k0 + i * 16 + quad * 4 + r;
                    if (needmask && kg > qg) v = -INFINITY;
                    sacc[i][qt][r] = v;
                    tm = fmaxf(tm, v);
                }
            tm = fmaxf(tm, __shfl_xor(tm, 16));
            tm = fmaxf(tm, __shfl_xor(tm, 32));
            float mold = mst[qt];
            float mnew = fmaxf(mold, tm);
            float alpha = __expf(mold - mnew);
            float suml = 0.0f;
            #pragma unroll
            for (int i = 0; i < 4; ++i) {
                float e0 = __expf(sacc[i][qt][0] - mnew);
                float e1 = __expf(sacc[i][qt][1] - mnew);
                float e2 = __expf(sacc[i][qt][2] - mnew);
                float e3 = __expf(sacc[i][qt][3] - mnew);
                suml += (e0 + e1) + (e2 + e3);
                uint2 u;
                u.x = (unsigned int)f2b(e0) | ((unsigned int)f2b(e1) << 16);
                u.y = (unsigned int)f2b(e2) | ((unsigned int)f2b(e3) << 16);
                *(uint2*)&Pt[w][(qt * 16 + l16) * PTP + i * 16 + quad * 4] = u;
            }
            suml += __shfl_xor(suml, 16);
            suml += __shfl_xor(suml, 32);
            lst[qt] = lst[qt] * alpha + suml;
            mst[qt] = mnew;
            // rescale O rows of this q-tile: row q = qt*16 + quad*4 + r
            #pragma unroll
            for (int r = 0; r < 4; ++r) {
                float ab = __shfl(alpha, quad * 4 + r);
                #pragma unroll
                for (int dt = 0; dt < 4; ++dt) oacc[qt][dt][r] *= ab;
            }
        }

        // O += P·V  (Pt wave-private: same-wave LDS ordering, no barrier)
        #pragma unroll
        for (int ch = 0; ch < 2; ++ch) {
            short8 pf[2], vf[4];
            #pragma unroll
            for (int mt = 0; mt < 2; ++mt)
                pf[mt] = *(const short8*)&Pt[w][(mt * 16 + l16) * PTP + ch * 32 + quad * 8];
            #pragma unroll
            for (int dt = 0; dt < 4; ++dt)
                vf[dt] = *(const short8*)&Vts[(dt * 16 + l16) * ATK + ch * 32 + quad * 8];
            #pragma unroll
            for (int mt = 0; mt < 2; ++mt)
                #pragma unroll
                for (int dt = 0; dt < 4; ++dt)
                    oacc[mt][dt] = __builtin_amdgcn_mfma_f32_16x16x32_bf16(pf[mt], vf[dt], oacc[mt][dt], 0, 0, 0);
        }
    }

    // epilogue: O row q = qbase + w*32 + mt*16 + quad*4 + r ; col d = dt*16+l16
    #pragma unroll
    for (int mt = 0; mt < 2; ++mt) {
        #pragma unroll
        for (int r = 0; r < 4; ++r) {
            float lr = __shfl(lst[mt], quad * 4 + r);
            float inv = 1.0f / lr;
            int qg = qbase + w * 32 + mt * 16 + quad * 4 + r;
            #pragma unroll
            for (int dt = 0; dt < 4; ++dt)
                out[(size_t)(b * SEQ + qg) * H + hh * 64 + dt * 16 + l16] =
                    f2b(oacc[mt][dt][r] * inv);
        }
    }
}

// ---------------------------------------------------------------- logits
__global__ __launch_bounds__(256) void logits_kernel(const float* __restrict__ xf,
                                                     const float* __restrict__ wte,
                                                     float* __restrict__ out) {
    int pair = blockIdx.x * 4 + (threadIdx.x >> 6);
    if (pair >= BATCH * VOCAB) return;
    int b = pair / VOCAB;
    int v = pair - b * VOCAB;
    int lane = threadIdx.x & 63;
    const float* w = wte + (size_t)v * H;
    const float* x = xf + (size_t)b * H;
    float s = 0.f;
    #pragma unroll
    for (int i = lane; i < H; i += 64) s += x[i] * w[i];
    #pragma unroll
    for (int off = 32; off > 0; off >>= 1) s += __shfl_down(s, off);
    if (lane == 0) out[(size_t)b * VOCAB + v] = s;
}

// ---------------------------------------------------------------- launch
extern "C" void kernel_launch(void* const* d_in, const int* in_sizes, int n_in,
                              void* d_out, int out_size, void* d_ws, size_t ws_size,
                              hipStream_t stream) {
    const int*   ids     = (const int*)d_in[0];
    const float* wte     = (const float*)d_in[1];
    const float* wpe     = (const float*)d_in[2];
    const float* ln1_g   = (const float*)d_in[3];
    const float* ln1_b   = (const float*)d_in[4];
    const float* qkv_w   = (const float*)d_in[5];
    const float* qkv_b   = (const float*)d_in[6];
    const float* dense_w = (const float*)d_in[7];
    const float* dense_b = (const float*)d_in[8];
    const float* ln2_g   = (const float*)d_in[9];
    const float* ln2_b   = (const float*)d_in[10];
    const float* fc1_w   = (const float*)d_in[11];
    const float* fc2_w   = (const float*)d_in[12];
    const float* fc2_b   = (const float*)d_in[13];
    const float* lnf_g   = (const float*)d_in[14];
    const float* lnf_b   = (const float*)d_in[15];
    float* outp = (float*)d_out;

    char* p = (char*)d_ws;
    float* x             = (float*)p;          p += (size_t)TOK * H * 4;
    unsigned short* h    = (unsigned short*)p; p += (size_t)TOK * H * 2;
    unsigned short* qkvb = (unsigned short*)p; p += (size_t)TOK * 3 * H * 2;
    unsigned short* attnb= (unsigned short*)p; p += (size_t)TOK * H * 2;
    unsigned short* ab   = (unsigned short*)p; p += (size_t)TOK * 2 * H * 2;
    unsigned short* wt   = (unsigned short*)p; p += (size_t)2304 * 768 * 2;
    float* xf            = (float*)p;          p += (size_t)BATCH * H * 4;
    unsigned short* vtb  = ab;   // alias: ab unused between qkv-GEMM and fc1

    embed_kernel<<<TOK, 256, 0, stream>>>(ids, wte, wpe, x);

    for (int l = 0; l < LAYERS; ++l) {
        ln_kernel<true><<<TOK, 256, 0, stream>>>(x, ln1_g + l * H, ln1_b + l * H, h, 1, 0);
        wconv_kernel<<<dim3(2304 / 64, 768 / 64), 256, 0, stream>>>(
            qkv_w + (size_t)l * H * 3 * H, wt, 768, 2304);
        gemm_bf16<<<dim3(2304 / GBN, TOK / GBM), 256, 0, stream>>>(
            h, wt, qkv_b + l * 3 * H, nullptr, qkvb, vtb, TOK, 2304, 768, 0);
        attn_mfma<<<BATCH * NH * NQTA, 256, 0, stream>>>(qkvb, vtb, attnb);
        wconv_kernel<<<dim3(768 / 64, 768 / 64), 256, 0, stream>>>(
            dense_w + (size_t)l * H * H, wt, 768, 768);
        gemm_bf16<<<dim3(768 / GBN, TOK / GBM), 256, 0, stream>>>(
            attnb, wt, dense_b + l * H, x, x, nullptr, TOK, 768, 768, 1);
        ln_kernel<true><<<TOK, 256, 0, stream>>>(x, ln2_g + l * H, ln2_b + l * H, h, 1, 0);
        wconv_kernel<<<dim3(1536 / 64, 768 / 64), 256, 0, stream>>>(
            fc1_w + (size_t)l * H * 2 * H, wt, 768, 1536);
        gemm_bf16<<<dim3(1536 / GBN, TOK / GBM), 256, 0, stream>>>(
            h, wt, nullptr, nullptr, ab, nullptr, TOK, 1536, 768, 2);
        wconv_kernel<<<dim3(768 / 64, 1536 / 64), 256, 0, stream>>>(
            fc2_w + (size_t)l * 2 * H * H, wt, 1536, 768);
        gemm_bf16<<<dim3(768 / GBN, TOK / GBM), 256, 0, stream>>>(
            ab, wt, fc2_b + l * H, x, x, nullptr, TOK, 768, 1536, 1);
    }

    ln_kernel<false><<<BATCH, 256, 0, stream>>>(x, lnf_g, lnf_b, xf, SEQ, SEQ - 1);
    logits_kernel<<<(BATCH * VOCAB + 3) / 4, 256, 0, stream>>>(xf, wte, outp);
}

// Round 5
// 1838.956 us; speedup vs baseline: 11.5839x; 1.0569x over previous
//
#include <hip/hip_runtime.h>
#include <math.h>

#define H 768
#define NH 12
#define DH 64
#define SEQ 2048
#define BATCH 2
#define TOK (BATCH*SEQ)   // 4096 rows
#define LAYERS 6
#define VOCAB 50257

// preconverted bf16 weight layout (per layer, element offsets)
#define WOFF_QKV   0
#define WSZ_QKV    (2304*768)
#define WOFF_DENSE (WOFF_QKV + WSZ_QKV)
#define WSZ_DENSE  (768*768)
#define WOFF_FC1   (WOFF_DENSE + WSZ_DENSE)
#define WSZ_FC1    (1536*768)
#define WOFF_FC2   (WOFF_FC1 + WSZ_FC1)
#define WSZ_FC2    (768*1536)
#define WSTRIDE    (WOFF_FC2 + WSZ_FC2)   // 4718592 elems/layer

typedef __attribute__((ext_vector_type(8))) short short8;
typedef __attribute__((ext_vector_type(4))) float floatx4;

__device__ __forceinline__ float bf2f(unsigned short u) {
    union { unsigned int i; float f; } v; v.i = ((unsigned int)u) << 16; return v.f;
}
__device__ __forceinline__ unsigned short f2b(float f) {
    union { float f; unsigned int i; } v; v.f = f;
    unsigned int u = v.i;
    return (unsigned short)((u + 0x7FFFu + ((u >> 16) & 1u)) >> 16);  // RNE
}
__device__ __forceinline__ void gload_lds16(const void* g, void* lds) {
    __builtin_amdgcn_global_load_lds((const __attribute__((address_space(1))) unsigned int*)g,
                                     (__attribute__((address_space(3))) unsigned int*)lds,
                                     16, 0, 0);
}

// ---------------------------------------------------------------- embed
__global__ __launch_bounds__(256) void embed_kernel(const int* __restrict__ ids,
                                                    const float* __restrict__ wte,
                                                    const float* __restrict__ wpe,
                                                    float* __restrict__ x) {
    int row = blockIdx.x;
    int s = row & (SEQ - 1);
    int id = ids[row];
    const float* wrow = wte + (size_t)id * H;
    const float* prow = wpe + (size_t)s * H;
    float* xrow = x + (size_t)row * H;
    for (int i = threadIdx.x; i < H; i += 256)
        xrow[i] = wrow[i] + prow[i];
}

// ---------------------------------------------------------------- layernorm
template <bool BF>
__global__ __launch_bounds__(256) void ln_kernel(const float* __restrict__ x,
                                                 const float* __restrict__ g,
                                                 const float* __restrict__ bb,
                                                 void* __restrict__ outv,
                                                 int rs, int ro) {
    __shared__ float red[4];
    __shared__ float mean_s, rstd_s;
    int row = blockIdx.x * rs + ro;
    const float* xr = x + (size_t)row * H;
    int t = threadIdx.x;
    float v0 = xr[t], v1 = xr[t + 256], v2 = xr[t + 512];
    float s = v0 + v1 + v2;
    #pragma unroll
    for (int off = 32; off > 0; off >>= 1) s += __shfl_down(s, off);
    int lane = t & 63, wid = t >> 6;
    if (lane == 0) red[wid] = s;
    __syncthreads();
    if (t == 0) mean_s = (red[0] + red[1] + red[2] + red[3]) * (1.0f / 768.0f);
    __syncthreads();
    float m = mean_s;
    float d0 = v0 - m, d1 = v1 - m, d2 = v2 - m;
    float q = d0 * d0 + d1 * d1 + d2 * d2;
    #pragma unroll
    for (int off = 32; off > 0; off >>= 1) q += __shfl_down(q, off);
    if (lane == 0) red[wid] = q;
    __syncthreads();
    if (t == 0) rstd_s = rsqrtf((red[0] + red[1] + red[2] + red[3]) * (1.0f / 768.0f) + 1e-12f);
    __syncthreads();
    float r = rstd_s;
    float o0 = d0 * r * g[t]       + bb[t];
    float o1 = d1 * r * g[t + 256] + bb[t + 256];
    float o2 = d2 * r * g[t + 512] + bb[t + 512];
    if (BF) {
        unsigned short* orow = (unsigned short*)outv + (size_t)blockIdx.x * H;
        orow[t] = f2b(o0); orow[t + 256] = f2b(o1); orow[t + 512] = f2b(o2);
    } else {
        float* orow = (float*)outv + (size_t)blockIdx.x * H;
        orow[t] = o0; orow[t + 256] = o1; orow[t + 512] = o2;
    }
}

// ---------------------------------------------------------------- all-layer weight convert: fp32[K,N] -> bf16[N,K]
// one launch for all 6 layers x {qkv,dense,fc1,fc2}; 64x64 tiles.
__global__ __launch_bounds__(256) void wconv_all(const float* __restrict__ qkv_w,
                                                 const float* __restrict__ dense_w,
                                                 const float* __restrict__ fc1_w,
                                                 const float* __restrict__ fc2_w,
                                                 unsigned short* __restrict__ wt) {
    __shared__ float tile[64][65];
    int bid = blockIdx.x;
    int l = bid / 1152;
    int r = bid % 1152;
    const float* W; unsigned short* D; int K, N, tn, tk;
    if (r < 432)      { W = qkv_w  + (size_t)l * 768 * 2304; D = wt + (size_t)l * WSTRIDE + WOFF_QKV;
                        K = 768;  N = 2304; tn = r % 36; tk = r / 36; }
    else if (r < 576) { r -= 432; W = dense_w + (size_t)l * 768 * 768; D = wt + (size_t)l * WSTRIDE + WOFF_DENSE;
                        K = 768;  N = 768;  tn = r % 12; tk = r / 12; }
    else if (r < 864) { r -= 576; W = fc1_w + (size_t)l * 768 * 1536; D = wt + (size_t)l * WSTRIDE + WOFF_FC1;
                        K = 768;  N = 1536; tn = r % 24; tk = r / 24; }
    else              { r -= 864; W = fc2_w + (size_t)l * 1536 * 768; D = wt + (size_t)l * WSTRIDE + WOFF_FC2;
                        K = 1536; N = 768;  tn = r % 12; tk = r / 12; }
    int n0 = tn * 64, k0 = tk * 64;
    int t = threadIdx.x;
    int rr = t >> 4, c = (t & 15) << 2;
    #pragma unroll
    for (int i = 0; i < 4; ++i) {
        float4 v = *(const float4*)(W + (size_t)(k0 + rr + 16 * i) * N + n0 + c);
        tile[rr + 16 * i][c + 0] = v.x; tile[rr + 16 * i][c + 1] = v.y;
        tile[rr + 16 * i][c + 2] = v.z; tile[rr + 16 * i][c + 3] = v.w;
    }
    __syncthreads();
    #pragma unroll
    for (int i = 0; i < 4; ++i) {
        int n = rr + 16 * i;
        ushort4 o;
        o.x = f2b(tile[c + 0][n]); o.y = f2b(tile[c + 1][n]);
        o.z = f2b(tile[c + 2][n]); o.w = f2b(tile[c + 3][n]);
        *(ushort4*)(D + (size_t)(n0 + n) * K + k0 + c) = o;
    }
}

// ---------------------------------------------------------------- bf16 MFMA GEMM (m97 structure)
// C[M,N] = A[M,K] @ Bt[N,K]^T
// mode 0: qkv epilogue (+bias; Q cols pre-scaled 1/8; V cols -> vtb transposed) -> bf16
// mode 1: +bias+res -> fp32 ; mode 2: gelu -> bf16
#define GBM 128
#define GBN 128
#define GBK 32
__global__ __launch_bounds__(256) void gemm_bf16(const unsigned short* __restrict__ A,
                                                 const unsigned short* __restrict__ Bt,
                                                 const float* __restrict__ bias,
                                                 const float* __restrict__ res,
                                                 void* __restrict__ Cv,
                                                 unsigned short* __restrict__ vtb,
                                                 int M, int N, int K, int mode) {
    __shared__ short As[GBM * GBK];
    __shared__ short Bs[GBN * GBK];
    int t = threadIdx.x;
    int w = t >> 6, lane = t & 63;
    int wr = w >> 1, wc = w & 1;
    int l16 = lane & 15, quad = lane >> 4;
    int bm = blockIdx.y * GBM, bn = blockIdx.x * GBN;

    floatx4 acc[4][4] = {};
    int srow = lane >> 2;
    int scol = (lane & 3) * 8;
    char* AsB = (char*)As + w * 2048;
    char* BsB = (char*)Bs + w * 2048;
    const unsigned short* Aw0 = A + (size_t)(bm + w * 32 + srow) * K + scol;
    const unsigned short* Aw1 = Aw0 + (size_t)16 * K;
    const unsigned short* Bw0 = Bt + (size_t)(bn + w * 32 + srow) * K + scol;
    const unsigned short* Bw1 = Bw0 + (size_t)16 * K;

    for (int k0 = 0; k0 < K; k0 += GBK) {
        __syncthreads();
        gload_lds16(Aw0 + k0, AsB);
        gload_lds16(Aw1 + k0, AsB + 1024);
        gload_lds16(Bw0 + k0, BsB);
        gload_lds16(Bw1 + k0, BsB + 1024);
        __syncthreads();
        short8 af[4], bfr[4];
        #pragma unroll
        for (int i = 0; i < 4; ++i)
            af[i] = *(const short8*)&As[(wr * 64 + i * 16 + l16) * GBK + quad * 8];
        #pragma unroll
        for (int i = 0; i < 4; ++i)
            bfr[i] = *(const short8*)&Bs[(wc * 64 + i * 16 + l16) * GBK + quad * 8];
        #pragma unroll
        for (int mi = 0; mi < 4; ++mi)
            #pragma unroll
            for (int ni = 0; ni < 4; ++ni)
                acc[mi][ni] = __builtin_amdgcn_mfma_f32_16x16x32_bf16(af[mi], bfr[ni], acc[mi][ni], 0, 0, 0);
    }

    int r0 = bm + wr * 64 + quad * 4;
    int c0 = bn + wc * 64 + l16;
    #pragma unroll
    for (int ni = 0; ni < 4; ++ni) {
        int gc = c0 + ni * 16;
        float bv = (mode != 2) ? bias[gc] : 0.0f;
        #pragma unroll
        for (int mi = 0; mi < 4; ++mi) {
            int gr = r0 + mi * 16;
            if (mode == 0 && gc >= 1536) {
                int hd = gc - 1536;
                int bb_ = gr >> 11, ss = gr & 2047;
                ushort4 o4;
                o4.x = f2b(acc[mi][ni][0] + bv);
                o4.y = f2b(acc[mi][ni][1] + bv);
                o4.z = f2b(acc[mi][ni][2] + bv);
                o4.w = f2b(acc[mi][ni][3] + bv);
                *(ushort4*)&vtb[((size_t)(bb_ * NH + (hd >> 6)) * 64 + (hd & 63)) * SEQ + ss] = o4;
            } else {
                #pragma unroll
                for (int reg = 0; reg < 4; ++reg) {
                    float v = acc[mi][ni][reg];
                    size_t idx = (size_t)(gr + reg) * N + gc;
                    if (mode == 2) {
                        v = 0.5f * v * (1.0f + erff(v * 0.70710678118654752f));
                        ((unsigned short*)Cv)[idx] = f2b(v);
                    } else if (mode == 0) {
                        v += bv;
                        if (gc < 768) v *= 0.125f;   // pre-scale Q (exact in bf16)
                        ((unsigned short*)Cv)[idx] = f2b(v);
                    } else {
                        ((float*)Cv)[idx] = v + bv + res[idx];
                    }
                }
            }
        }
    }
}

// ---------------------------------------------------------------- attention: MFMA flash
#define ATQ 128
#define ATK 64
#define PTP 72
#define NQTA (SEQ/ATQ)  // 16
__global__ __launch_bounds__(256) void attn_mfma(const unsigned short* __restrict__ qkv,
                                                 const unsigned short* __restrict__ vt,
                                                 unsigned short* __restrict__ out) {
    __shared__ unsigned short Qs[ATQ * 64];
    __shared__ unsigned short Ks[ATK * 64];
    __shared__ unsigned short Vts[64 * ATK];
    __shared__ unsigned short Pt[4][32 * PTP];

    int idx = blockIdx.x;
    int bh = idx % (BATCH * NH);
    int qt_blk = (NQTA - 1) - idx / (BATCH * NH);
    int b = bh / NH, hh = bh % NH;
    int qbase = qt_blk * ATQ;
    const size_t rstride = 3 * H;
    const unsigned short* base = qkv + (size_t)b * SEQ * rstride;
    const unsigned short* vbase = vt + (size_t)bh * DH * SEQ;

    int t = threadIdx.x;
    int w = t >> 6, lane = t & 63;
    int l16 = lane & 15, quad = lane >> 4;

    #pragma unroll
    for (int i = 0; i < 4; ++i) {
        int row = w * 32 + i * 8 + (lane >> 3);
        int col = (lane & 7) * 8;
        gload_lds16(base + (size_t)(qbase + row) * rstride + hh * 64 + col,
                    Qs + w * 2048 + i * 512);
    }
    __syncthreads();

    short8 qf[2][2];
    #pragma unroll
    for (int qt = 0; qt < 2; ++qt)
        #pragma unroll
        for (int ch = 0; ch < 2; ++ch)
            qf[qt][ch] = *(const short8*)&Qs[(w * 32 + qt * 16 + l16) * 64 + ch * 32 + quad * 8];

    float mst[2] = {-INFINITY, -INFINITY};
    float lst[2] = {0.0f, 0.0f};
    floatx4 oacc[2][4] = {};

    int ntiles = (qbase + ATQ) / ATK;
    for (int kt = 0; kt < ntiles; ++kt) {
        int k0 = kt * ATK;
        __syncthreads();
        #pragma unroll
        for (int i = 0; i < 2; ++i) {
            int row = w * 16 + i * 8 + (lane >> 3);
            int col = (lane & 7) * 8;
            gload_lds16(base + (size_t)(k0 + row) * rstride + H + hh * 64 + col,
                        Ks + w * 1024 + i * 512);
            gload_lds16(vbase + (size_t)row * SEQ + k0 + col,
                        Vts + w * 1024 + i * 512);
        }
        __syncthreads();

        floatx4 sacc[4][2] = {};
        #pragma unroll
        for (int ch = 0; ch < 2; ++ch) {
            short8 kf[4];
            #pragma unroll
            for (int i = 0; i < 4; ++i)
                kf[i] = *(const short8*)&Ks[(i * 16 + l16) * 64 + ch * 32 + quad * 8];
            #pragma unroll
            for (int i = 0; i < 4; ++i)
                #pragma unroll
                for (int qt = 0; qt < 2; ++qt)
                    sacc[i][qt] = __builtin_amdgcn_mfma_f32_16x16x32_bf16(kf[i], qf[qt][ch], sacc[i][qt], 0, 0, 0);
        }

        bool needmask = (k0 + ATK - 1) > (qbase + w * 32);
        #pragma unroll
        for (int qt = 0; qt < 2; ++qt) {
            int qg = qbase + w * 32 + qt * 16 + l16;
            float tm = -INFINITY;
            #pragma unroll
            for (int i = 0; i < 4; ++i)
                #pragma unroll
                for (int r = 0; r < 4; ++r) {
                    float v = sacc[i][qt][r];
                    int kg = k0 + i * 16 + quad * 4 + r;
                    if (needmask && kg > qg) v = -INFINITY;
                    sacc[i][qt][r] = v;
                    tm = fmaxf(tm, v);
                }
            tm = fmaxf(tm, __shfl_xor(tm, 16));
            tm = fmaxf(tm, __shfl_xor(tm, 32));
            float mold = mst[qt];
            float mnew = fmaxf(mold, tm);
            float alpha = __expf(mold - mnew);
            float suml = 0.0f;
            #pragma unroll
            for (int i = 0; i < 4; ++i) {
                float e0 = __expf(sacc[i][qt][0] - mnew);
                float e1 = __expf(sacc[i][qt][1] - mnew);
                float e2 = __expf(sacc[i][qt][2] - mnew);
                float e3 = __expf(sacc[i][qt][3] - mnew);
                suml += (e0 + e1) + (e2 + e3);
                uint2 u;
                u.x = (unsigned int)f2b(e0) | ((unsigned int)f2b(e1) << 16);
                u.y = (unsigned int)f2b(e2) | ((unsigned int)f2b(e3) << 16);
                *(uint2*)&Pt[w][(qt * 16 + l16) * PTP + i * 16 + quad * 4] = u;
            }
            suml += __shfl_xor(suml, 16);
            suml += __shfl_xor(suml, 32);
            lst[qt] = lst[qt] * alpha + suml;
            mst[qt] = mnew;
            #pragma unroll
            for (int r = 0; r < 4; ++r) {
                float ab = __shfl(alpha, quad * 4 + r);
                #pragma unroll
                for (int dt = 0; dt < 4; ++dt) oacc[qt][dt][r] *= ab;
            }
        }

        #pragma unroll
        for (int ch = 0; ch < 2; ++ch) {
            short8 pf[2], vf[4];
            #pragma unroll
            for (int mt = 0; mt < 2; ++mt)
                pf[mt] = *(const short8*)&Pt[w][(mt * 16 + l16) * PTP + ch * 32 + quad * 8];
            #pragma unroll
            for (int dt = 0; dt < 4; ++dt)
                vf[dt] = *(const short8*)&Vts[(dt * 16 + l16) * ATK + ch * 32 + quad * 8];
            #pragma unroll
            for (int mt = 0; mt < 2; ++mt)
                #pragma unroll
                for (int dt = 0; dt < 4; ++dt)
                    oacc[mt][dt] = __builtin_amdgcn_mfma_f32_16x16x32_bf16(pf[mt], vf[dt], oacc[mt][dt], 0, 0, 0);
        }
    }

    #pragma unroll
    for (int mt = 0; mt < 2; ++mt) {
        #pragma unroll
        for (int r = 0; r < 4; ++r) {
            float lr = __shfl(lst[mt], quad * 4 + r);
            float inv = 1.0f / lr;
            int qg = qbase + w * 32 + mt * 16 + quad * 4 + r;
            #pragma unroll
            for (int dt = 0; dt < 4; ++dt)
                out[(size_t)(b * SEQ + qg) * H + hh * 64 + dt * 16 + l16] =
                    f2b(oacc[mt][dt][r] * inv);
        }
    }
}

// ---------------------------------------------------------------- logits
// one wave per vocab row; float4 loads; both batches share the w-row read.
__global__ __launch_bounds__(256) void logits_kernel(const float* __restrict__ xf,
                                                     const float* __restrict__ wte,
                                                     float* __restrict__ out) {
    int v = blockIdx.x * 4 + (threadIdx.x >> 6);
    if (v >= VOCAB) return;
    int lane = threadIdx.x & 63;
    const float* w = wte + (size_t)v * H + lane * 4;
    const float* x0 = xf + lane * 4;
    const float* x1 = xf + H + lane * 4;
    float4 w0 = *(const float4*)(w);
    float4 w1 = *(const float4*)(w + 256);
    float4 w2 = *(const float4*)(w + 512);
    float4 a0 = *(const float4*)(x0);
    float4 a1 = *(const float4*)(x0 + 256);
    float4 a2 = *(const float4*)(x0 + 512);
    float4 b0 = *(const float4*)(x1);
    float4 b1 = *(const float4*)(x1 + 256);
    float4 b2 = *(const float4*)(x1 + 512);
    float s0 = w0.x*a0.x + w0.y*a0.y + w0.z*a0.z + w0.w*a0.w
             + w1.x*a1.x + w1.y*a1.y + w1.z*a1.z + w1.w*a1.w
             + w2.x*a2.x + w2.y*a2.y + w2.z*a2.z + w2.w*a2.w;
    float s1 = w0.x*b0.x + w0.y*b0.y + w0.z*b0.z + w0.w*b0.w
             + w1.x*b1.x + w1.y*b1.y + w1.z*b1.z + w1.w*b1.w
             + w2.x*b2.x + w2.y*b2.y + w2.z*b2.z + w2.w*b2.w;
    #pragma unroll
    for (int off = 32; off > 0; off >>= 1) {
        s0 += __shfl_down(s0, off);
        s1 += __shfl_down(s1, off);
    }
    if (lane == 0) {
        out[v] = s0;
        out[VOCAB + v] = s1;
    }
}

// ---------------------------------------------------------------- launch
extern "C" void kernel_launch(void* const* d_in, const int* in_sizes, int n_in,
                              void* d_out, int out_size, void* d_ws, size_t ws_size,
                              hipStream_t stream) {
    const int*   ids     = (const int*)d_in[0];
    const float* wte     = (const float*)d_in[1];
    const float* wpe     = (const float*)d_in[2];
    const float* ln1_g   = (const float*)d_in[3];
    const float* ln1_b   = (const float*)d_in[4];
    const float* qkv_w   = (const float*)d_in[5];
    const float* qkv_b   = (const float*)d_in[6];
    const float* dense_w = (const float*)d_in[7];
    const float* dense_b = (const float*)d_in[8];
    const float* ln2_g   = (const float*)d_in[9];
    const float* ln2_b   = (const float*)d_in[10];
    const float* fc1_w   = (const float*)d_in[11];
    const float* fc2_w   = (const float*)d_in[12];
    const float* fc2_b   = (const float*)d_in[13];
    const float* lnf_g   = (const float*)d_in[14];
    const float* lnf_b   = (const float*)d_in[15];
    float* outp = (float*)d_out;

    char* p = (char*)d_ws;
    float* x             = (float*)p;          p += (size_t)TOK * H * 4;
    unsigned short* h    = (unsigned short*)p; p += (size_t)TOK * H * 2;
    unsigned short* qkvb = (unsigned short*)p; p += (size_t)TOK * 3 * H * 2;
    unsigned short* attnb= (unsigned short*)p; p += (size_t)TOK * H * 2;
    unsigned short* ab   = (unsigned short*)p; p += (size_t)TOK * 2 * H * 2;
    unsigned short* wt   = (unsigned short*)p; p += (size_t)WSTRIDE * LAYERS * 2;
    float* xf            = (float*)p;          p += (size_t)BATCH * H * 4;
    unsigned short* vtb  = ab;   // alias: ab unused between qkv-GEMM and fc1

    embed_kernel<<<TOK, 256, 0, stream>>>(ids, wte, wpe, x);
    wconv_all<<<LAYERS * 1152, 256, 0, stream>>>(qkv_w, dense_w, fc1_w, fc2_w, wt);

    for (int l = 0; l < LAYERS; ++l) {
        const unsigned short* wl = wt + (size_t)l * WSTRIDE;
        ln_kernel<true><<<TOK, 256, 0, stream>>>(x, ln1_g + l * H, ln1_b + l * H, h, 1, 0);
        gemm_bf16<<<dim3(2304 / GBN, TOK / GBM), 256, 0, stream>>>(
            h, wl + WOFF_QKV, qkv_b + l * 3 * H, nullptr, qkvb, vtb, TOK, 2304, 768, 0);
        attn_mfma<<<BATCH * NH * NQTA, 256, 0, stream>>>(qkvb, vtb, attnb);
        gemm_bf16<<<dim3(768 / GBN, TOK / GBM), 256, 0, stream>>>(
            attnb, wl + WOFF_DENSE, dense_b + l * H, x, x, nullptr, TOK, 768, 768, 1);
        ln_kernel<true><<<TOK, 256, 0, stream>>>(x, ln2_g + l * H, ln2_b + l * H, h, 1, 0);
        gemm_bf16<<<dim3(1536 / GBN, TOK / GBM), 256, 0, stream>>>(
            h, wl + WOFF_FC1, nullptr, nullptr, ab, nullptr, TOK, 1536, 768, 2);
        gemm_bf16<<<dim3(768 / GBN, TOK / GBM), 256, 0, stream>>>(
            ab, wl + WOFF_FC2, fc2_b + l * H, x, x, nullptr, TOK, 768, 1536, 1);
    }

    ln_kernel<false><<<BATCH, 256, 0, stream>>>(x, lnf_g, lnf_b, xf, SEQ, SEQ - 1);
    logits_kernel<<<(VOCAB + 3) / 4, 256, 0, stream>>>(xf, wte, outp);
}